// Round 7
// baseline (741.104 us; speedup 1.0000x reference)
//
#include <hip/hip_runtime.h>
#include <math.h>

#define NN   20000
#define TT   32
#define INF_ 32
#define HID  64
#define NH   4
#define EE   320000
#define ETOT (EE + NN)
#define ZROW 164   // shorts/row: 160 data + 4 pad; 82 dw ≡ 18 mod 32 -> 16-bank node spread
#define NB   80    // nodes per LSTM block; 250*80 = 20000 exact
#define GNP  84    // G node-stride (80 + 4 pad): write banks = lq*16+ln15 -> 2-way free

typedef __attribute__((ext_vector_type(8))) short bf16x8;
typedef __attribute__((ext_vector_type(4))) short short4v;
typedef __attribute__((ext_vector_type(4))) float f32x4;

static __device__ __forceinline__ float sigf(float x){ return 1.0f/(1.0f+__expf(-x)); }
static __device__ __forceinline__ float tanhf_(float x){ float e=__expf(2.0f*x); return 1.0f - 2.0f/(e+1.0f); }
static __device__ __forceinline__ float lrelu(float x){ return x>0.0f ? x : 0.2f*x; }

static __device__ __forceinline__ unsigned short f2bf(float f){
  unsigned u = __float_as_uint(f);
  unsigned r = u + 0x7fffu + ((u>>16)&1u);
  return (unsigned short)(r>>16);
}
static __device__ __forceinline__ float bf2f(unsigned short h){ return __uint_as_float(((unsigned)h)<<16); }

static __device__ __forceinline__ void edge_sd(const int* __restrict__ ei, int e, int& s, int& d){
  if (e < EE){ s = ei[e]; d = ei[EE + e]; } else { s = e - EE; d = s; }
}

// ---------------- utility kernels ----------------
__global__ void kzero_int(int* __restrict__ p, int n){
  int i = blockIdx.x*256 + threadIdx.x;
  if (i < n) p[i] = 0;
}

// Pack weights into MFMA A-fragment layout (split bf16 hi/lo) + bias sums. (verified R3)
__global__ void pack_weights(const float* __restrict__ Wih0, const float* __restrict__ Whh0,
                             const float* __restrict__ bih0, const float* __restrict__ bhh0,
                             const float* __restrict__ Wih1, const float* __restrict__ Whh1,
                             const float* __restrict__ bih1, const float* __restrict__ bhh1,
                             unsigned short* __restrict__ Wpk,
                             float* __restrict__ b0, float* __restrict__ b1){
  int idx = blockIdx.x*256 + threadIdx.x;
  if (idx < 49152){
    int fb = idx >> 9;          // 0..95
    int h  = fb & 1;
    int t2 = fb >> 1;           // 0..47
    int ks = t2 % 3, w = t2 / 3;
    int r  = idx & 511;
    int l  = r >> 3, j = r & 7;
    int gate = w*16 + (l & 15);
    int k = ks*32 + 4*(l>>4) + (j & 3) + 16*(j >> 2);
    float src = (k < 32) ? Wih0[gate*32 + k] : Whh0[gate*64 + (k - 32)];
    unsigned short hi = f2bf(src);
    Wpk[idx] = h ? f2bf(src - bf2f(hi)) : hi;
  } else if (idx < 114688){
    int idx2 = idx - 49152;
    int fb = idx2 >> 9;         // 0..127
    int h  = fb & 1;
    int t2 = fb >> 1;           // 0..63
    int ks = t2 & 3, w = t2 >> 2;
    int r  = idx2 & 511;
    int l  = r >> 3, j = r & 7;
    int gate = w*16 + (l & 15);
    int k = ks*32 + 4*(l>>4) + (j & 3) + 16*(j >> 2);   // 0..127
    float src = (k < 64) ? Wih1[gate*64 + k] : Whh1[gate*64 + (k - 64)];
    unsigned short hi = f2bf(src);
    Wpk[idx] = h ? f2bf(src - bf2f(hi)) : hi;
  } else {
    int m = idx - 114688;
    if (m < 256) b0[m] = bih0[m] + bhh0[m];
    else if (m < 512) b1[m-256] = bih1[m-256] + bhh1[m-256];
  }
}

// ---------------- CSR build (dst-indexed) ----------------
__global__ void count_deg(const int* __restrict__ ei, int* __restrict__ deg){
  int e = blockIdx.x*256 + threadIdx.x;
  if (e >= ETOT) return;
  int s, d; edge_sd(ei, e, s, d);
  atomicAdd(deg + d, 1);
}

__global__ void scan_deg(const int* __restrict__ deg, int* __restrict__ indptr, int* __restrict__ cursor){
  __shared__ int part[256];
  const int t = threadIdx.x;
  const int CH = (NN + 255) / 256;
  const int c0 = t * CH;
  int sum = 0;
  for (int i=0;i<CH;i++){ int idx=c0+i; if (idx<NN) sum += deg[idx]; }
  part[t] = sum; __syncthreads();
  int val = sum;
  for (int off=1; off<256; off<<=1){
    int add = (t>=off) ? part[t-off] : 0;
    __syncthreads();
    val += add; part[t] = val;
    __syncthreads();
  }
  int run = val - sum;
  for (int i=0;i<CH;i++){
    int idx=c0+i;
    if (idx<NN){ indptr[idx]=run; cursor[idx]=run; run += deg[idx]; }
  }
  if (t == 0) indptr[NN] = ETOT;
}

__global__ void scatter_edges(const int* __restrict__ ei, int* __restrict__ cursor, int* __restrict__ csr_src){
  int e = blockIdx.x*256 + threadIdx.x;
  if (e >= ETOT) return;
  int s, d; edge_sd(ei, e, s, d);
  int pos = atomicAdd(cursor + d, 1);
  csr_src[pos] = s;
}

// ---------------- MFMA split-bf16 2-layer LSTM (80 nodes/block, 1 grid round) ----------------
// 16 waves; wave w owns gates w*16..+15, weights resident. Z linear ZROW=164 (bank-spread 16),
// ZFRAG = 2x ds_read_b64. G = [gate][unit][node(+pad 84)]: scalar writes 2-way free.
__global__ __launch_bounds__(1024)
__attribute__((amdgpu_waves_per_eu(4,4)))
void lstm_mfma(
    const float* __restrict__ x,
    const unsigned short* __restrict__ Wpk,
    const float* __restrict__ b0, const float* __restrict__ b1,
    float* __restrict__ h1out)
{
  __shared__ unsigned short Zh[NB*ZROW];   // 25.6 KB
  __shared__ unsigned short Zl[NB*ZROW];   // 25.6 KB
  __shared__ float G[4*64*GNP];            // 84.0 KB

  const int tid  = threadIdx.x;
  const int lane = tid & 63;
  const int w    = __builtin_amdgcn_readfirstlane(tid >> 6);   // 0..15
  const int ln15 = lane & 15;
  const int lq   = lane >> 4;                                  // 0..3
  const int gbase = blockIdx.x * NB;

  // ---- resident weight fragments ----
  const bf16x8* wp = (const bf16x8*)Wpk;
  bf16x8 wA0h[3], wA0l[3], wA1h[4], wA1l[4];
#pragma unroll
  for (int ks=0; ks<3; ++ks){
    wA0h[ks] = wp[((w*3 + ks)*2 + 0)*64 + lane];
    wA0l[ks] = wp[((w*3 + ks)*2 + 1)*64 + lane];
  }
#pragma unroll
  for (int ks=0; ks<4; ++ks){
    wA1h[ks] = wp[6144 + ((w*4 + ks)*2 + 0)*64 + lane];
    wA1l[ks] = wp[6144 + ((w*4 + ks)*2 + 1)*64 + lane];
  }
  float bv0[4], bv1[4];
#pragma unroll
  for (int r=0; r<4; ++r){
    bv0[r] = b0[w*16 + lq*4 + r];
    bv1[r] = b1[w*16 + lq*4 + r];
  }

  // pointwise mapping: unit pu = tid>>4, node-low ps = tid&15; 5 nodes (a*16+ps)
  const int pu = tid >> 4;
  const int ps = tid & 15;
  float c0[5], c1[5];
#pragma unroll
  for (int i=0;i<5;i++){ c0[i]=0.f; c1[i]=0.f; }

  // x staging: threads 0..639; node xn=tid>>3, k-quad xk=(tid&7)*4 (linear slots)
  const int xn = tid >> 3;
  const int xk = (tid & 7) * 4;
  const float* xbase = x + (size_t)(gbase + ((xn < NB) ? xn : 0))*(TT*INF_) + xk;
  const bool xth = (tid < 640);

  // G write: wave w -> gate qg, units ub..ub+3
  const int qg = w >> 2;
  const int ub = (w & 3)*16 + lq*4;

  // ---- prologue: zero Z, stage x(0) ----
  for (int i = tid; i < NB*ZROW; i += 1024){ Zh[i] = 0; Zl[i] = 0; }
  __syncthreads();
  if (xth){
    const float4 xv = *(const float4*)(xbase + 0);
    unsigned short h_[4], l_[4];
    h_[0]=f2bf(xv.x); h_[1]=f2bf(xv.y); h_[2]=f2bf(xv.z); h_[3]=f2bf(xv.w);
    l_[0]=f2bf(xv.x-bf2f(h_[0])); l_[1]=f2bf(xv.y-bf2f(h_[1]));
    l_[2]=f2bf(xv.z-bf2f(h_[2])); l_[3]=f2bf(xv.w-bf2f(h_[3]));
    *(uint2*)&Zh[xn*ZROW + xk] = make_uint2((unsigned)h_[0]|((unsigned)h_[1]<<16), (unsigned)h_[2]|((unsigned)h_[3]<<16));
    *(uint2*)&Zl[xn*ZROW + xk] = make_uint2((unsigned)l_[0]|((unsigned)l_[1]<<16), (unsigned)l_[2]|((unsigned)l_[3]<<16));
  }
  __syncthreads();

#define ZFRAG(Zb, node, kz) ({                                            \
    const unsigned short* _p = &Zb[(node)*ZROW + (kz) + 4*lq];            \
    short4v _a = *(const short4v*)_p;                                     \
    short4v _b = *(const short4v*)(_p + 16);                              \
    __builtin_shufflevector(_a, _b, 0,1,2,3,4,5,6,7); })

#define MF(acc, A, B) acc = __builtin_amdgcn_mfma_f32_16x16x32_bf16((A),(B),(acc),0,0,0)

#define GRP(ACC, GG, KZ, WH, WL) {                                        \
    bf16x8 zh = ZFRAG(Zh, (GG)*16+ln15, KZ);                              \
    bf16x8 zl = ZFRAG(Zl, (GG)*16+ln15, KZ);                              \
    MF(ACC, WH, zh); MF(ACC, WH, zl); MF(ACC, WL, zh); }

#define GSTORE(ACC, GG) {                                                 \
    const int _n = (GG)*16 + ln15;                                        \
    G[(qg*64 + ub + 0)*GNP + _n] = ACC[0];                                \
    G[(qg*64 + ub + 1)*GNP + _n] = ACC[1];                                \
    G[(qg*64 + ub + 2)*GNP + _n] = ACC[2];                                \
    G[(qg*64 + ub + 3)*GNP + _n] = ACC[3]; }

  for (int t=0; t<TT; ++t){
    // ================= Phase A: L0 MFMA (k-chunks 0..2) =================
    {
      f32x4 a0,a1,a2,a3,a4;
      a0=a1=a2=a3=a4=(f32x4){bv0[0],bv0[1],bv0[2],bv0[3]};
#pragma unroll
      for (int ks=0; ks<3; ++ks){
        const int kz = ks*32;
        const bf16x8 wh = wA0h[ks], wl = wA0l[ks];
        GRP(a0,0,kz,wh,wl); GRP(a1,1,kz,wh,wl); GRP(a2,2,kz,wh,wl);
        GRP(a3,3,kz,wh,wl); GRP(a4,4,kz,wh,wl);
      }
      GSTORE(a0,0); GSTORE(a1,1); GSTORE(a2,2); GSTORE(a3,3); GSTORE(a4,4);
    }
    __syncthreads();

    // ================= Phase B: pointwise L0 -> h0, stage x(t+1) =================
    {
      float4 xv;
      const bool dox = xth && (t+1 < TT);
      if (dox) xv = *(const float4*)(xbase + (size_t)(t+1)*INF_);
#pragma unroll
      for (int a=0; a<5; ++a){
        const int n = a*16 + ps;
        const float gi = G[(0*64+pu)*GNP + n];
        const float gf = G[(1*64+pu)*GNP + n];
        const float gg = G[(2*64+pu)*GNP + n];
        const float go = G[(3*64+pu)*GNP + n];
        const float cc = sigf(gf)*c0[a] + sigf(gi)*tanhf_(gg);
        c0[a] = cc;
        const float hv = sigf(go)*tanhf_(cc);
        const unsigned short hh = f2bf(hv);
        Zh[n*ZROW + 32 + pu] = hh;
        Zl[n*ZROW + 32 + pu] = f2bf(hv - bf2f(hh));
      }
      if (dox){
        unsigned short h_[4], l_[4];
        h_[0]=f2bf(xv.x); h_[1]=f2bf(xv.y); h_[2]=f2bf(xv.z); h_[3]=f2bf(xv.w);
        l_[0]=f2bf(xv.x-bf2f(h_[0])); l_[1]=f2bf(xv.y-bf2f(h_[1]));
        l_[2]=f2bf(xv.z-bf2f(h_[2])); l_[3]=f2bf(xv.w-bf2f(h_[3]));
        *(uint2*)&Zh[xn*ZROW + xk] = make_uint2((unsigned)h_[0]|((unsigned)h_[1]<<16), (unsigned)h_[2]|((unsigned)h_[3]<<16));
        *(uint2*)&Zl[xn*ZROW + xk] = make_uint2((unsigned)l_[0]|((unsigned)l_[1]<<16), (unsigned)l_[2]|((unsigned)l_[3]<<16));
      }
    }
    __syncthreads();

    // ================= Phase C: L1 MFMA (k-chunks 1..4) =================
    {
      f32x4 a0,a1,a2,a3,a4;
      a0=a1=a2=a3=a4=(f32x4){bv1[0],bv1[1],bv1[2],bv1[3]};
#pragma unroll
      for (int ks=0; ks<4; ++ks){
        const int kz = 32 + ks*32;
        const bf16x8 wh = wA1h[ks], wl = wA1l[ks];
        GRP(a0,0,kz,wh,wl); GRP(a1,1,kz,wh,wl); GRP(a2,2,kz,wh,wl);
        GRP(a3,3,kz,wh,wl); GRP(a4,4,kz,wh,wl);
      }
      GSTORE(a0,0); GSTORE(a1,1); GSTORE(a2,2); GSTORE(a3,3); GSTORE(a4,4);
    }
    __syncthreads();

    // ================= Phase D: pointwise L1 -> h1 =================
#pragma unroll
    for (int a=0; a<5; ++a){
      const int n = a*16 + ps;
      const float gi = G[(0*64+pu)*GNP + n];
      const float gf = G[(1*64+pu)*GNP + n];
      const float gg = G[(2*64+pu)*GNP + n];
      const float go = G[(3*64+pu)*GNP + n];
      const float cc = sigf(gf)*c1[a] + sigf(gi)*tanhf_(gg);
      c1[a] = cc;
      const float hv = sigf(go)*tanhf_(cc);
      const unsigned short hh = f2bf(hv);
      Zh[n*ZROW + 96 + pu] = hh;
      Zl[n*ZROW + 96 + pu] = f2bf(hv - bf2f(hh));
    }
    __syncthreads();
  }

  // ---- epilogue: coalesced h1 write ----
  for (int o = tid; o < NB*64; o += 1024){
    const int n = o >> 6, u = o & 63;
    h1out[(size_t)(gbase+n)*64 + u] = bf2f(Zh[n*ZROW + 96 + u]) + bf2f(Zl[n*ZROW + 96 + u]);
  }
#undef ZFRAG
#undef MF
#undef GRP
#undef GSTORE
}

// ---------------- GAT layer 1 prep ----------------
__global__ __launch_bounds__(256) void gat1_prep(const float* __restrict__ h1, const float* __restrict__ W,
  const float* __restrict__ as_, const float* __restrict__ ad_,
  float* __restrict__ xh, float* __restrict__ als, float* __restrict__ ald)
{
  const int nb = blockIdx.x;
  const int o  = threadIdx.x;
  const int q  = o >> 6, u = o & 63;
  const float* hp = h1 + (size_t)nb*64;
  float acc = 0.f;
#pragma unroll 8
  for (int k=0;k<64;k++) acc = fmaf(hp[k], W[k*256 + o], acc);
  xh[(size_t)nb*256 + o] = acc;
  float ps = acc * as_[o];
  float pd = acc * ad_[o];
#pragma unroll
  for (int off=32; off>=1; off>>=1){ ps += __shfl_xor(ps, off); pd += __shfl_xor(pd, off); }
  if (u == 0){ als[nb*4 + q] = ps; ald[nb*4 + q] = pd; }
}

// ---------------- GAT1 gather + fused epilogue ----------------
__global__ __launch_bounds__(256) void gat1_gather(
  const int* __restrict__ indptr, const int* __restrict__ csr_src,
  const float* __restrict__ als, const float* __restrict__ ald,
  const float* __restrict__ xh,  const float* __restrict__ b1g,
  const float* __restrict__ w2,  const float* __restrict__ as2, const float* __restrict__ ad2,
  float* __restrict__ xh2, float* __restrict__ a2s, float* __restrict__ a2d)
{
  const int d = blockIdx.x*4 + (threadIdx.x >> 6);
  const int lane = threadIdx.x & 63;
  if (d >= NN) return;
  const int p0 = indptr[d], p1 = indptr[d+1];

  float aldv[4];
#pragma unroll
  for (int q=0;q<4;q++) aldv[q] = ald[d*4+q];

  float mx[4];
#pragma unroll
  for (int q=0;q<4;q++) mx[q] = -3.4e38f;
  for (int e=p0+lane; e<p1; e+=64){
    int s = csr_src[e];
#pragma unroll
    for (int q=0;q<4;q++){
      float ev = lrelu(als[s*4+q] + aldv[q]);
      mx[q] = fmaxf(mx[q], ev);
    }
  }
#pragma unroll
  for (int off=32; off>=1; off>>=1){
#pragma unroll
    for (int q=0;q<4;q++) mx[q] = fmaxf(mx[q], __shfl_xor(mx[q], off));
  }

  const int q = lane >> 4;
  const float mq = mx[q];
  const float aldq = aldv[q];
  float ax=0.f, ay=0.f, az=0.f, aw=0.f, den=0.f;
  int s_next = (p0 < p1) ? csr_src[p0] : 0;
  for (int e=p0; e<p1; ++e){
    const int s = s_next;
    if (e+1 < p1) s_next = csr_src[e+1];
    float ev = lrelu(als[s*4+q] + aldq);
    float ex = __expf(ev - mq);
    den += ex;
    float4 v = *(const float4*)(xh + (size_t)s*256 + lane*4);
    ax = fmaf(ex, v.x, ax); ay = fmaf(ex, v.y, ay);
    az = fmaf(ex, v.z, az); aw = fmaf(ex, v.w, aw);
  }
  const float rr = 1.0f/(den + 1e-16f);
  const int o = lane*4;
  float v0 = ax*rr + b1g[o+0];
  float v1 = ay*rr + b1g[o+1];
  float v2 = az*rr + b1g[o+2];
  float v3 = aw*rr + b1g[o+3];
  v0 = v0>0.f?v0:0.f; v1 = v1>0.f?v1:0.f; v2 = v2>0.f?v2:0.f; v3 = v3>0.f?v3:0.f;
  float part = v0*w2[o+0] + v1*w2[o+1] + v2*w2[o+2] + v3*w2[o+3];
#pragma unroll
  for (int off=32; off>=1; off>>=1) part += __shfl_xor(part, off);
  if (lane == 0){
    xh2[d] = part;
    a2s[d] = part * as2[0];
    a2d[d] = part * ad2[0];
  }
}

// ---------------- GAT2 gather ----------------
__global__ __launch_bounds__(256) void gat2_gather(
  const int* __restrict__ indptr, const int* __restrict__ csr_src,
  const float* __restrict__ a2s, const float* __restrict__ a2d,
  const float* __restrict__ xh2, const float* __restrict__ b2,
  float* __restrict__ out)
{
  const int d = blockIdx.x*4 + (threadIdx.x >> 6);
  const int lane = threadIdx.x & 63;
  if (d >= NN) return;
  const int p0 = indptr[d], p1 = indptr[d+1];
  const float add = a2d[d];

  float mx = -3.4e38f;
  for (int e=p0+lane; e<p1; e+=64){
    int s = csr_src[e];
    mx = fmaxf(mx, lrelu(a2s[s] + add));
  }
#pragma unroll
  for (int off=32; off>=1; off>>=1) mx = fmaxf(mx, __shfl_xor(mx, off));

  float den = 0.f, num = 0.f;
  for (int e=p0+lane; e<p1; e+=64){
    int s = csr_src[e];
    float ev = lrelu(a2s[s] + add);
    float ex = __expf(ev - mx);
    den += ex;
    num = fmaf(ex, xh2[s], num);
  }
#pragma unroll
  for (int off=32; off>=1; off>>=1){ den += __shfl_xor(den, off); num += __shfl_xor(num, off); }
  if (lane == 0) out[d] = num/(den + 1e-16f) + b2[0];
}

// ---------------- launcher ----------------
extern "C" void kernel_launch(void* const* d_in, const int* in_sizes, int n_in,
                              void* d_out, int out_size, void* d_ws, size_t ws_size,
                              hipStream_t stream)
{
  const float* x    = (const float*)d_in[0];
  const int*   ei   = (const int*)d_in[1];
  const float* Wih0 = (const float*)d_in[2];
  const float* Whh0 = (const float*)d_in[3];
  const float* bih0 = (const float*)d_in[4];
  const float* bhh0 = (const float*)d_in[5];
  const float* Wih1 = (const float*)d_in[6];
  const float* Whh1 = (const float*)d_in[7];
  const float* bih1 = (const float*)d_in[8];
  const float* bhh1 = (const float*)d_in[9];
  const float* g1w  = (const float*)d_in[10];
  const float* g1as = (const float*)d_in[11];
  const float* g1ad = (const float*)d_in[12];
  const float* g1b  = (const float*)d_in[13];
  const float* g2w  = (const float*)d_in[14];
  const float* g2as = (const float*)d_in[15];
  const float* g2ad = (const float*)d_in[16];
  const float* g2b  = (const float*)d_in[17];

  float* ws  = (float*)d_ws;
  unsigned short* Wpk = (unsigned short*)ws;   // 114688 shorts = 57344 f32 slots
  float* b0  = ws + 57344;            // 256
  float* b1  = b0 + 256;              // 256
  float* h1  = b1 + 256;              // 20000*64
  float* xh  = h1 + 1280000;          // 20000*256
  float* als = xh + 5120000;          // 80000
  float* ald = als + 80000;           // 80000
  float* xh2 = ald + 80000;           // 20000
  float* a2s = xh2 + 20000;           // 20000
  float* a2d = a2s + 20000;           // 20000
  int*   deg    = (int*)(a2d + 20000);   // 20000
  int*   indptr = deg + 20000;           // 20001
  int*   cursor = indptr + 20001;        // 20000
  int*   csr    = cursor + 20000;        // 340000

  kzero_int<<<(NN+255)/256, 256, 0, stream>>>(deg, NN);
  pack_weights<<<450, 256, 0, stream>>>(Wih0,Whh0,bih0,bhh0,Wih1,Whh1,bih1,bhh1,Wpk,b0,b1);
  count_deg<<<(ETOT+255)/256, 256, 0, stream>>>(ei, deg);
  scan_deg<<<1, 256, 0, stream>>>(deg, indptr, cursor);
  scatter_edges<<<(ETOT+255)/256, 256, 0, stream>>>(ei, cursor, csr);
  lstm_mfma<<<250, 1024, 0, stream>>>(x, Wpk, b0, b1, h1);
  gat1_prep<<<NN, 256, 0, stream>>>(h1, g1w, g1as, g1ad, xh, als, ald);
  gat1_gather<<<(NN+3)/4, 256, 0, stream>>>(indptr, csr, als, ald, xh, g1b, g2w, g2as, g2ad, xh2, a2s, a2d);
  gat2_gather<<<(NN+3)/4, 256, 0, stream>>>(indptr, csr, a2s, a2d, xh2, g2b, (float*)d_out);
}

// Round 8
// 459.136 us; speedup vs baseline: 1.6141x; 1.6141x over previous
//
#include <hip/hip_runtime.h>
#include <math.h>

#define NN   20000
#define TT   32
#define INF_ 32
#define HID  64
#define NH   4
#define EE   320000
#define ETOT (EE + NN)
#define ZROW 164   // shorts/row: 160 data + 4 pad; node stride 41 x 8B-units (odd) -> b64 conflict-free
#define NB   80    // nodes per LSTM block; 250*80 = 20000 exact

typedef __attribute__((ext_vector_type(8))) short bf16x8;
typedef __attribute__((ext_vector_type(4))) short short4v;
typedef __attribute__((ext_vector_type(4))) float f32x4;

static __device__ __forceinline__ float lrelu(float x){ return x>0.0f ? x : 0.2f*x; }

static __device__ __forceinline__ unsigned short f2bf(float f){
  unsigned u = __float_as_uint(f);
  unsigned r = u + 0x7fffu + ((u>>16)&1u);
  return (unsigned short)(r>>16);
}
static __device__ __forceinline__ float bf2f(unsigned short h){ return __uint_as_float(((unsigned)h)<<16); }

// fused LSTM cell: 5 exp + 2 rcp (vs ~10 trans naive)
static __device__ __forceinline__ float lstm_cell(float gi, float gf, float gg, float go, float& c){
  float ef = __expf(-gf), ei = __expf(-gi), eg = __expf(-2.0f*gg);
  float pN = c*(1.0f+ei)*(1.0f+eg) + (1.0f-eg)*(1.0f+ef);
  float pD = (1.0f+ef)*(1.0f+ei)*(1.0f+eg);
  float cc = pN * __builtin_amdgcn_rcpf(pD);
  c = cc;
  float eo = __expf(-go), ec = __expf(-2.0f*cc);
  return (1.0f-ec) * __builtin_amdgcn_rcpf((1.0f+eo)*(1.0f+ec));
}

static __device__ __forceinline__ void edge_sd(const int* __restrict__ ei, int e, int& s, int& d){
  if (e < EE){ s = ei[e]; d = ei[EE + e]; } else { s = e - EE; d = s; }
}

// ---------------- utility kernels ----------------
__global__ void kzero_int(int* __restrict__ p, int n){
  int i = blockIdx.x*256 + threadIdx.x;
  if (i < n) p[i] = 0;
}

// Pack weights into MFMA A-frag layout, rows PERMUTED so C/D row = 4*unitLocal + gateType
// -> pointwise is per-lane in-register. Split bf16 hi/lo. Frag elem: row=l&15,
// k = ks*32 + 4*(l>>4) + (j&3) + 16*(j>>2). gate row g = (pr&3)*64 + w*8 + T*4 + (pr>>2).
__global__ void pack_weights(const float* __restrict__ Wih0, const float* __restrict__ Whh0,
                             const float* __restrict__ bih0, const float* __restrict__ bhh0,
                             const float* __restrict__ Wih1, const float* __restrict__ Whh1,
                             const float* __restrict__ bih1, const float* __restrict__ bhh1,
                             unsigned short* __restrict__ Wpk,
                             float* __restrict__ b0, float* __restrict__ b1){
  int idx = blockIdx.x*256 + threadIdx.x;
  if (idx < 49152){
    int fb = idx >> 9;            // 0..95 : ((w*2+T)*3+ks)*2+h
    int h  = fb & 1;
    int t2 = fb >> 1;             // 0..47
    int ks = t2 % 3, T2 = t2 / 3; // T2 = w*2+T
    int T  = T2 & 1, w = T2 >> 1;
    int r  = idx & 511;
    int l  = r >> 3, j = r & 7;
    int pr = l & 15;
    int g  = (pr&3)*64 + w*8 + T*4 + (pr>>2);
    int k  = ks*32 + 4*(l>>4) + (j & 3) + 16*(j >> 2);
    float src = (k < 32) ? Wih0[g*32 + k] : Whh0[g*64 + (k - 32)];
    unsigned short hi = f2bf(src);
    Wpk[idx] = h ? f2bf(src - bf2f(hi)) : hi;
  } else if (idx < 114688){
    int idx2 = idx - 49152;
    int fb = idx2 >> 9;           // 0..127 : ((w*2+T)*4+ks)*2+h
    int h  = fb & 1;
    int t2 = fb >> 1;             // 0..63
    int ks = t2 & 3, T2 = t2 >> 2;
    int T  = T2 & 1, w = T2 >> 1;
    int r  = idx2 & 511;
    int l  = r >> 3, j = r & 7;
    int pr = l & 15;
    int g  = (pr&3)*64 + w*8 + T*4 + (pr>>2);
    int k  = ks*32 + 4*(l>>4) + (j & 3) + 16*(j >> 2);  // 0..127
    float src = (k < 64) ? Wih1[g*64 + k] : Whh1[g*64 + (k - 64)];
    unsigned short hi = f2bf(src);
    Wpk[idx] = h ? f2bf(src - bf2f(hi)) : hi;
  } else {
    int m = idx - 114688;
    if (m < 256) b0[m] = bih0[m] + bhh0[m];
    else if (m < 512) b1[m-256] = bih1[m-256] + bhh1[m-256];
  }
}

// ---------------- CSR build (dst-indexed) ----------------
__global__ void count_deg(const int* __restrict__ ei, int* __restrict__ deg){
  int e = blockIdx.x*256 + threadIdx.x;
  if (e >= ETOT) return;
  int s, d; edge_sd(ei, e, s, d);
  atomicAdd(deg + d, 1);
}

__global__ void scan_deg(const int* __restrict__ deg, int* __restrict__ indptr, int* __restrict__ cursor){
  __shared__ int part[256];
  const int t = threadIdx.x;
  const int CH = (NN + 255) / 256;
  const int c0 = t * CH;
  int sum = 0;
  for (int i=0;i<CH;i++){ int idx=c0+i; if (idx<NN) sum += deg[idx]; }
  part[t] = sum; __syncthreads();
  int val = sum;
  for (int off=1; off<256; off<<=1){
    int add = (t>=off) ? part[t-off] : 0;
    __syncthreads();
    val += add; part[t] = val;
    __syncthreads();
  }
  int run = val - sum;
  for (int i=0;i<CH;i++){
    int idx=c0+i;
    if (idx<NN){ indptr[idx]=run; cursor[idx]=run; run += deg[idx]; }
  }
  if (t == 0) indptr[NN] = ETOT;
}

__global__ void scatter_edges(const int* __restrict__ ei, int* __restrict__ cursor, int* __restrict__ csr_src){
  int e = blockIdx.x*256 + threadIdx.x;
  if (e >= ETOT) return;
  int s, d; edge_sd(ei, e, s, d);
  int pos = atomicAdd(cursor + d, 1);
  csr_src[pos] = s;
}

// ---------------- MFMA split-bf16 2-layer LSTM: 8 waves, in-register pointwise ----------------
// Wave w owns units w*8..w*8+7 (2 tiles of 16 packed rows = 4 units x 4 gates).
// Z = [x(0..31)|h0(32..95)|h1(96..159)] bf16 hi/lo, LDS only 52.5KB. No G exchange.
// 3-phase/t: P1=[L0 MFMA || L1-pointwise(t-1)], P2=[L1 MFMA h1-slabs || L0-pointwise], P3=[L1 MFMA h0-slabs].
__global__ __launch_bounds__(512, 2)
__attribute__((amdgpu_waves_per_eu(2, 2)))
void lstm_mfma(
    const float* __restrict__ x,
    const unsigned short* __restrict__ Wpk,
    const float* __restrict__ b0, const float* __restrict__ b1,
    float* __restrict__ h1out)
{
  __shared__ unsigned short Zh[NB*ZROW];   // 26.2 KB
  __shared__ unsigned short Zl[NB*ZROW];   // 26.2 KB

  const int tid  = threadIdx.x;
  const int lane = tid & 63;
  const int w    = __builtin_amdgcn_readfirstlane(tid >> 6);   // 0..7
  const int ln15 = lane & 15;
  const int lq   = lane >> 4;                                  // 0..3
  const int gbase = blockIdx.x * NB;

  const bf16x8* wp = (const bf16x8*)Wpk;

  // bias per lane: bv[T][j] = b[j*64 + w*8 + T*4 + lq]
  f32x4 bv0[2], bv1[2];
#pragma unroll
  for (int T=0; T<2; ++T){
    const int u = w*8 + T*4 + lq;
#pragma unroll
    for (int j=0; j<4; ++j){ bv0[T][j] = b0[j*64+u]; bv1[T][j] = b1[j*64+u]; }
  }

  // x staging: quads q1=tid, q2=512+tid (tid<128); node=q>>3, k=(q&7)*4
  const int xn1 = tid >> 3,        xk1 = (tid & 7)*4;
  const int xn2 = (512+tid) >> 3,  xk2 = ((512+tid) & 7)*4;
  const float* xp1 = x + (size_t)(gbase + xn1)*(TT*INF_) + xk1;
  const float* xp2 = x + (size_t)(gbase + xn2)*(TT*INF_) + xk2;
  const bool x2 = (tid < 128);

  // ---- prologue: zero Z, stage x(0) ----
  for (int i = tid; i < NB*ZROW/2; i += 512){ ((unsigned*)Zh)[i] = 0; ((unsigned*)Zl)[i] = 0; }
  __syncthreads();
  {
    float4 v = *(const float4*)xp1;
    unsigned short h_[4], l_[4];
    h_[0]=f2bf(v.x); h_[1]=f2bf(v.y); h_[2]=f2bf(v.z); h_[3]=f2bf(v.w);
    l_[0]=f2bf(v.x-bf2f(h_[0])); l_[1]=f2bf(v.y-bf2f(h_[1]));
    l_[2]=f2bf(v.z-bf2f(h_[2])); l_[3]=f2bf(v.w-bf2f(h_[3]));
    *(uint2*)&Zh[xn1*ZROW + xk1] = make_uint2((unsigned)h_[0]|((unsigned)h_[1]<<16),(unsigned)h_[2]|((unsigned)h_[3]<<16));
    *(uint2*)&Zl[xn1*ZROW + xk1] = make_uint2((unsigned)l_[0]|((unsigned)l_[1]<<16),(unsigned)l_[2]|((unsigned)l_[3]<<16));
    if (x2){
      float4 u = *(const float4*)xp2;
      h_[0]=f2bf(u.x); h_[1]=f2bf(u.y); h_[2]=f2bf(u.z); h_[3]=f2bf(u.w);
      l_[0]=f2bf(u.x-bf2f(h_[0])); l_[1]=f2bf(u.y-bf2f(h_[1]));
      l_[2]=f2bf(u.z-bf2f(h_[2])); l_[3]=f2bf(u.w-bf2f(h_[3]));
      *(uint2*)&Zh[xn2*ZROW + xk2] = make_uint2((unsigned)h_[0]|((unsigned)h_[1]<<16),(unsigned)h_[2]|((unsigned)h_[3]<<16));
      *(uint2*)&Zl[xn2*ZROW + xk2] = make_uint2((unsigned)l_[0]|((unsigned)l_[1]<<16),(unsigned)l_[2]|((unsigned)l_[3]<<16));
    }
  }
  __syncthreads();

  float c0[10], c1[10];   // [T*5+GG]
#pragma unroll
  for (int i=0;i<10;i++){ c0[i]=0.f; c1[i]=0.f; }
  f32x4 aL1[2][5];

#define ZFRAG(Zb, node, kz) ({                                            \
    const unsigned short* _p = &Zb[(node)*ZROW + (kz) + 4*lq];            \
    short4v _a = *(const short4v*)_p;                                     \
    short4v _b = *(const short4v*)(_p + 16);                              \
    __builtin_shufflevector(_a, _b, 0,1,2,3,4,5,6,7); })

#define MF(acc, A, B) acc = __builtin_amdgcn_mfma_f32_16x16x32_bf16((A),(B),(acc),0,0,0)

#define HWRITE(hv, col) {                                                 \
    const unsigned short _hh = f2bf(hv);                                  \
    Zh[_n*ZROW + (col)] = _hh;                                            \
    Zl[_n*ZROW + (col)] = f2bf((hv) - bf2f(_hh)); }

  for (int t=0; t<TT; ++t){
    // ====== P1: issue x(t+1) loads; L1-pointwise(t-1) -> H1; L0 MFMA (reads Z 0..95) ======
    float4 xv1, xv2;
    const bool dox = (t+1 < TT);
    if (dox){ xv1 = *(const float4*)(xp1 + (size_t)(t+1)*INF_);
              if (x2) xv2 = *(const float4*)(xp2 + (size_t)(t+1)*INF_); }

    f32x4 aL0[2][5];
#pragma unroll
    for (int T=0; T<2; ++T)
#pragma unroll
      for (int GG=0; GG<5; ++GG) aL0[T][GG] = bv0[T];

    if (t > 0){
#pragma unroll
      for (int T=0; T<2; ++T){
        const int uc = 96 + w*8 + T*4 + lq;
#pragma unroll
        for (int GG=0; GG<5; ++GG){
          const int _n = GG*16 + ln15;
          float h = lstm_cell(aL1[T][GG][0], aL1[T][GG][1], aL1[T][GG][2], aL1[T][GG][3], c1[T*5+GG]);
          HWRITE(h, uc);
        }
      }
    }

#pragma unroll
    for (int ks=0; ks<3; ++ks){
      const int kz = ks*32;
      const bf16x8 wh0 = wp[(((w*2+0)*3+ks)*2+0)*64 + lane];
      const bf16x8 wl0 = wp[(((w*2+0)*3+ks)*2+1)*64 + lane];
      const bf16x8 wh1 = wp[(((w*2+1)*3+ks)*2+0)*64 + lane];
      const bf16x8 wl1 = wp[(((w*2+1)*3+ks)*2+1)*64 + lane];
#pragma unroll
      for (int GG=0; GG<5; ++GG){
        const bf16x8 zh = ZFRAG(Zh, GG*16+ln15, kz);
        const bf16x8 zl = ZFRAG(Zl, GG*16+ln15, kz);
        MF(aL0[0][GG], wh0, zh); MF(aL0[0][GG], wh0, zl); MF(aL0[0][GG], wl0, zh);
        MF(aL0[1][GG], wh1, zh); MF(aL0[1][GG], wh1, zl); MF(aL0[1][GG], wl1, zh);
      }
    }
    __syncthreads();

    // ====== P2: L1 MFMA slabs 2,3 (reads H1) || L0-pointwise -> H0 + x(t+1) write ======
#pragma unroll
    for (int T=0; T<2; ++T)
#pragma unroll
      for (int GG=0; GG<5; ++GG) aL1[T][GG] = bv1[T];

#pragma unroll
    for (int ks=2; ks<4; ++ks){
      const int kz = 32 + ks*32;   // 96, 128
      const bf16x8 wh0 = wp[6144 + (((w*2+0)*4+ks)*2+0)*64 + lane];
      const bf16x8 wl0 = wp[6144 + (((w*2+0)*4+ks)*2+1)*64 + lane];
      const bf16x8 wh1 = wp[6144 + (((w*2+1)*4+ks)*2+0)*64 + lane];
      const bf16x8 wl1 = wp[6144 + (((w*2+1)*4+ks)*2+1)*64 + lane];
#pragma unroll
      for (int GG=0; GG<5; ++GG){
        const bf16x8 zh = ZFRAG(Zh, GG*16+ln15, kz);
        const bf16x8 zl = ZFRAG(Zl, GG*16+ln15, kz);
        MF(aL1[0][GG], wh0, zh); MF(aL1[0][GG], wh0, zl); MF(aL1[0][GG], wl0, zh);
        MF(aL1[1][GG], wh1, zh); MF(aL1[1][GG], wh1, zl); MF(aL1[1][GG], wl1, zh);
      }
    }

#pragma unroll
    for (int T=0; T<2; ++T){
      const int uc = 32 + w*8 + T*4 + lq;
#pragma unroll
      for (int GG=0; GG<5; ++GG){
        const int _n = GG*16 + ln15;
        float h = lstm_cell(aL0[T][GG][0], aL0[T][GG][1], aL0[T][GG][2], aL0[T][GG][3], c0[T*5+GG]);
        HWRITE(h, uc);
      }
    }
    if (dox){
      unsigned short h_[4], l_[4];
      h_[0]=f2bf(xv1.x); h_[1]=f2bf(xv1.y); h_[2]=f2bf(xv1.z); h_[3]=f2bf(xv1.w);
      l_[0]=f2bf(xv1.x-bf2f(h_[0])); l_[1]=f2bf(xv1.y-bf2f(h_[1]));
      l_[2]=f2bf(xv1.z-bf2f(h_[2])); l_[3]=f2bf(xv1.w-bf2f(h_[3]));
      *(uint2*)&Zh[xn1*ZROW + xk1] = make_uint2((unsigned)h_[0]|((unsigned)h_[1]<<16),(unsigned)h_[2]|((unsigned)h_[3]<<16));
      *(uint2*)&Zl[xn1*ZROW + xk1] = make_uint2((unsigned)l_[0]|((unsigned)l_[1]<<16),(unsigned)l_[2]|((unsigned)l_[3]<<16));
      if (x2){
        h_[0]=f2bf(xv2.x); h_[1]=f2bf(xv2.y); h_[2]=f2bf(xv2.z); h_[3]=f2bf(xv2.w);
        l_[0]=f2bf(xv2.x-bf2f(h_[0])); l_[1]=f2bf(xv2.y-bf2f(h_[1]));
        l_[2]=f2bf(xv2.z-bf2f(h_[2])); l_[3]=f2bf(xv2.w-bf2f(h_[3]));
        *(uint2*)&Zh[xn2*ZROW + xk2] = make_uint2((unsigned)h_[0]|((unsigned)h_[1]<<16),(unsigned)h_[2]|((unsigned)h_[3]<<16));
        *(uint2*)&Zl[xn2*ZROW + xk2] = make_uint2((unsigned)l_[0]|((unsigned)l_[1]<<16),(unsigned)l_[2]|((unsigned)l_[3]<<16));
      }
    }
    __syncthreads();

    // ====== P3: L1 MFMA slabs 0,1 (reads H0 just written) ======
#pragma unroll
    for (int ks=0; ks<2; ++ks){
      const int kz = 32 + ks*32;   // 32, 64
      const bf16x8 wh0 = wp[6144 + (((w*2+0)*4+ks)*2+0)*64 + lane];
      const bf16x8 wl0 = wp[6144 + (((w*2+0)*4+ks)*2+1)*64 + lane];
      const bf16x8 wh1 = wp[6144 + (((w*2+1)*4+ks)*2+0)*64 + lane];
      const bf16x8 wl1 = wp[6144 + (((w*2+1)*4+ks)*2+1)*64 + lane];
#pragma unroll
      for (int GG=0; GG<5; ++GG){
        const bf16x8 zh = ZFRAG(Zh, GG*16+ln15, kz);
        const bf16x8 zl = ZFRAG(Zl, GG*16+ln15, kz);
        MF(aL1[0][GG], wh0, zh); MF(aL1[0][GG], wh0, zl); MF(aL1[0][GG], wl0, zh);
        MF(aL1[1][GG], wh1, zh); MF(aL1[1][GG], wh1, zl); MF(aL1[1][GG], wl1, zh);
      }
    }
    __syncthreads();
  }

  // final L1 pointwise -> H1
#pragma unroll
  for (int T=0; T<2; ++T){
    const int uc = 96 + w*8 + T*4 + lq;
#pragma unroll
    for (int GG=0; GG<5; ++GG){
      const int _n = GG*16 + ln15;
      float h = lstm_cell(aL1[T][GG][0], aL1[T][GG][1], aL1[T][GG][2], aL1[T][GG][3], c1[T*5+GG]);
      HWRITE(h, uc);
    }
  }
  __syncthreads();

  // epilogue: coalesced h1 write
  for (int o = tid; o < NB*64; o += 512){
    const int n = o >> 6, u = o & 63;
    h1out[(size_t)(gbase+n)*64 + u] = bf2f(Zh[n*ZROW + 96 + u]) + bf2f(Zl[n*ZROW + 96 + u]);
  }
#undef ZFRAG
#undef MF
#undef HWRITE
}

// ---------------- GAT layer 1 prep ----------------
__global__ __launch_bounds__(256) void gat1_prep(const float* __restrict__ h1, const float* __restrict__ W,
  const float* __restrict__ as_, const float* __restrict__ ad_,
  float* __restrict__ xh, float* __restrict__ als, float* __restrict__ ald)
{
  const int nb = blockIdx.x;
  const int o  = threadIdx.x;
  const int q  = o >> 6, u = o & 63;
  const float* hp = h1 + (size_t)nb*64;
  float acc = 0.f;
#pragma unroll 8
  for (int k=0;k<64;k++) acc = fmaf(hp[k], W[k*256 + o], acc);
  xh[(size_t)nb*256 + o] = acc;
  float ps = acc * as_[o];
  float pd = acc * ad_[o];
#pragma unroll
  for (int off=32; off>=1; off>>=1){ ps += __shfl_xor(ps, off); pd += __shfl_xor(pd, off); }
  if (u == 0){ als[nb*4 + q] = ps; ald[nb*4 + q] = pd; }
}

// ---------------- GAT1 gather + fused epilogue ----------------
__global__ __launch_bounds__(256) void gat1_gather(
  const int* __restrict__ indptr, const int* __restrict__ csr_src,
  const float* __restrict__ als, const float* __restrict__ ald,
  const float* __restrict__ xh,  const float* __restrict__ b1g,
  const float* __restrict__ w2,  const float* __restrict__ as2, const float* __restrict__ ad2,
  float* __restrict__ xh2, float* __restrict__ a2s, float* __restrict__ a2d)
{
  const int d = blockIdx.x*4 + (threadIdx.x >> 6);
  const int lane = threadIdx.x & 63;
  if (d >= NN) return;
  const int p0 = indptr[d], p1 = indptr[d+1];

  float aldv[4];
#pragma unroll
  for (int q=0;q<4;q++) aldv[q] = ald[d*4+q];

  float mx[4];
#pragma unroll
  for (int q=0;q<4;q++) mx[q] = -3.4e38f;
  for (int e=p0+lane; e<p1; e+=64){
    int s = csr_src[e];
#pragma unroll
    for (int q=0;q<4;q++){
      float ev = lrelu(als[s*4+q] + aldv[q]);
      mx[q] = fmaxf(mx[q], ev);
    }
  }
#pragma unroll
  for (int off=32; off>=1; off>>=1){
#pragma unroll
    for (int q=0;q<4;q++) mx[q] = fmaxf(mx[q], __shfl_xor(mx[q], off));
  }

  const int q = lane >> 4;
  const float mq = mx[q];
  const float aldq = aldv[q];
  float ax=0.f, ay=0.f, az=0.f, aw=0.f, den=0.f;
  int s_next = (p0 < p1) ? csr_src[p0] : 0;
  for (int e=p0; e<p1; ++e){
    const int s = s_next;
    if (e+1 < p1) s_next = csr_src[e+1];
    float ev = lrelu(als[s*4+q] + aldq);
    float ex = __expf(ev - mq);
    den += ex;
    float4 v = *(const float4*)(xh + (size_t)s*256 + lane*4);
    ax = fmaf(ex, v.x, ax); ay = fmaf(ex, v.y, ay);
    az = fmaf(ex, v.z, az); aw = fmaf(ex, v.w, aw);
  }
  const float rr = 1.0f/(den + 1e-16f);
  const int o = lane*4;
  float v0 = ax*rr + b1g[o+0];
  float v1 = ay*rr + b1g[o+1];
  float v2 = az*rr + b1g[o+2];
  float v3 = aw*rr + b1g[o+3];
  v0 = v0>0.f?v0:0.f; v1 = v1>0.f?v1:0.f; v2 = v2>0.f?v2:0.f; v3 = v3>0.f?v3:0.f;
  float part = v0*w2[o+0] + v1*w2[o+1] + v2*w2[o+2] + v3*w2[o+3];
#pragma unroll
  for (int off=32; off>=1; off>>=1) part += __shfl_xor(part, off);
  if (lane == 0){
    xh2[d] = part;
    a2s[d] = part * as2[0];
    a2d[d] = part * ad2[0];
  }
}

// ---------------- GAT2 gather ----------------
__global__ __launch_bounds__(256) void gat2_gather(
  const int* __restrict__ indptr, const int* __restrict__ csr_src,
  const float* __restrict__ a2s, const float* __restrict__ a2d,
  const float* __restrict__ xh2, const float* __restrict__ b2,
  float* __restrict__ out)
{
  const int d = blockIdx.x*4 + (threadIdx.x >> 6);
  const int lane = threadIdx.x & 63;
  if (d >= NN) return;
  const int p0 = indptr[d], p1 = indptr[d+1];
  const float add = a2d[d];

  float mx = -3.4e38f;
  for (int e=p0+lane; e<p1; e+=64){
    int s = csr_src[e];
    mx = fmaxf(mx, lrelu(a2s[s] + add));
  }
#pragma unroll
  for (int off=32; off>=1; off>>=1) mx = fmaxf(mx, __shfl_xor(mx, off));

  float den = 0.f, num = 0.f;
  for (int e=p0+lane; e<p1; e+=64){
    int s = csr_src[e];
    float ev = lrelu(a2s[s] + add);
    float ex = __expf(ev - mx);
    den += ex;
    num = fmaf(ex, xh2[s], num);
  }
#pragma unroll
  for (int off=32; off>=1; off>>=1){ den += __shfl_xor(den, off); num += __shfl_xor(num, off); }
  if (lane == 0) out[d] = num/(den + 1e-16f) + b2[0];
}

// ---------------- launcher ----------------
extern "C" void kernel_launch(void* const* d_in, const int* in_sizes, int n_in,
                              void* d_out, int out_size, void* d_ws, size_t ws_size,
                              hipStream_t stream)
{
  const float* x    = (const float*)d_in[0];
  const int*   ei   = (const int*)d_in[1];
  const float* Wih0 = (const float*)d_in[2];
  const float* Whh0 = (const float*)d_in[3];
  const float* bih0 = (const float*)d_in[4];
  const float* bhh0 = (const float*)d_in[5];
  const float* Wih1 = (const float*)d_in[6];
  const float* Whh1 = (const float*)d_in[7];
  const float* bih1 = (const float*)d_in[8];
  const float* bhh1 = (const float*)d_in[9];
  const float* g1w  = (const float*)d_in[10];
  const float* g1as = (const float*)d_in[11];
  const float* g1ad = (const float*)d_in[12];
  const float* g1b  = (const float*)d_in[13];
  const float* g2w  = (const float*)d_in[14];
  const float* g2as = (const float*)d_in[15];
  const float* g2ad = (const float*)d_in[16];
  const float* g2b  = (const float*)d_in[17];

  float* ws  = (float*)d_ws;
  unsigned short* Wpk = (unsigned short*)ws;   // 114688 shorts = 57344 f32 slots
  float* b0  = ws + 57344;            // 256
  float* b1  = b0 + 256;              // 256
  float* h1  = b1 + 256;              // 20000*64
  float* xh  = h1 + 1280000;          // 20000*256
  float* als = xh + 5120000;          // 80000
  float* ald = als + 80000;           // 80000
  float* xh2 = ald + 80000;           // 20000
  float* a2s = xh2 + 20000;           // 20000
  float* a2d = a2s + 20000;           // 20000
  int*   deg    = (int*)(a2d + 20000);   // 20000
  int*   indptr = deg + 20000;           // 20001
  int*   cursor = indptr + 20001;        // 20000
  int*   csr    = cursor + 20000;        // 340000

  kzero_int<<<(NN+255)/256, 256, 0, stream>>>(deg, NN);
  pack_weights<<<450, 256, 0, stream>>>(Wih0,Whh0,bih0,bhh0,Wih1,Whh1,bih1,bhh1,Wpk,b0,b1);
  count_deg<<<(ETOT+255)/256, 256, 0, stream>>>(ei, deg);
  scan_deg<<<1, 256, 0, stream>>>(deg, indptr, cursor);
  scatter_edges<<<(ETOT+255)/256, 256, 0, stream>>>(ei, cursor, csr);
  lstm_mfma<<<250, 512, 0, stream>>>(x, Wpk, b0, b1, h1);
  gat1_prep<<<NN, 256, 0, stream>>>(h1, g1w, g1as, g1ad, xh, als, ald);
  gat1_gather<<<(NN+3)/4, 256, 0, stream>>>(indptr, csr, als, ald, xh, g1b, g2w, g2as, g2ad, xh2, a2s, a2d);
  gat2_gather<<<(NN+3)/4, 256, 0, stream>>>(indptr, csr, a2s, a2d, xh2, g2b, (float*)d_out);
}

// Round 9
// 420.954 us; speedup vs baseline: 1.7605x; 1.0907x over previous
//
#include <hip/hip_runtime.h>
#include <math.h>

#define NN   20000
#define TT   32
#define INF_ 32
#define HID  64
#define NH   4
#define EE   320000
#define ETOT (EE + NN)
#define ZROW 164   // shorts/row: 160 data + 4 pad; node stride 41x8B-units (odd) -> b64 conflict-free
#define NB   80    // nodes per LSTM block; 250*80 = 20000 exact

typedef __attribute__((ext_vector_type(8))) short bf16x8;
typedef __attribute__((ext_vector_type(4))) short short4v;
typedef __attribute__((ext_vector_type(4))) float f32x4;

static __device__ __forceinline__ float lrelu(float x){ return x>0.0f ? x : 0.2f*x; }

static __device__ __forceinline__ unsigned short f2bf(float f){
  unsigned u = __float_as_uint(f);
  unsigned r = u + 0x7fffu + ((u>>16)&1u);
  return (unsigned short)(r>>16);
}
static __device__ __forceinline__ float bf2f(unsigned short h){ return __uint_as_float(((unsigned)h)<<16); }

// fused LSTM cell: 5 exp + 2 rcp
static __device__ __forceinline__ float lstm_cell(float gi, float gf, float gg, float go, float& c){
  float ef = __expf(-gf), ei = __expf(-gi), eg = __expf(-2.0f*gg);
  float pN = c*(1.0f+ei)*(1.0f+eg) + (1.0f-eg)*(1.0f+ef);
  float pD = (1.0f+ef)*(1.0f+ei)*(1.0f+eg);
  float cc = pN * __builtin_amdgcn_rcpf(pD);
  c = cc;
  float eo = __expf(-go), ec = __expf(-2.0f*cc);
  return (1.0f-ec) * __builtin_amdgcn_rcpf((1.0f+eo)*(1.0f+ec));
}

static __device__ __forceinline__ void edge_sd(const int* __restrict__ ei, int e, int& s, int& d){
  if (e < EE){ s = ei[e]; d = ei[EE + e]; } else { s = e - EE; d = s; }
}

// ---------------- utility kernels ----------------
__global__ void kzero_int(int* __restrict__ p, int n){
  int i = blockIdx.x*256 + threadIdx.x;
  if (i < n) p[i] = 0;
}

// Pack weights into MFMA A-frag layout, rows permuted so C/D row = 4*unitLocal + gateType. (verified R7)
__global__ void pack_weights(const float* __restrict__ Wih0, const float* __restrict__ Whh0,
                             const float* __restrict__ bih0, const float* __restrict__ bhh0,
                             const float* __restrict__ Wih1, const float* __restrict__ Whh1,
                             const float* __restrict__ bih1, const float* __restrict__ bhh1,
                             unsigned short* __restrict__ Wpk,
                             float* __restrict__ b0, float* __restrict__ b1){
  int idx = blockIdx.x*256 + threadIdx.x;
  if (idx < 49152){
    int fb = idx >> 9;            // ((w*2+T)*3+ks)*2+h
    int h  = fb & 1;
    int t2 = fb >> 1;
    int ks = t2 % 3, T2 = t2 / 3;
    int T  = T2 & 1, w = T2 >> 1;
    int r  = idx & 511;
    int l  = r >> 3, j = r & 7;
    int pr = l & 15;
    int g  = (pr&3)*64 + w*8 + T*4 + (pr>>2);
    int k  = ks*32 + 4*(l>>4) + (j & 3) + 16*(j >> 2);
    float src = (k < 32) ? Wih0[g*32 + k] : Whh0[g*64 + (k - 32)];
    unsigned short hi = f2bf(src);
    Wpk[idx] = h ? f2bf(src - bf2f(hi)) : hi;
  } else if (idx < 114688){
    int idx2 = idx - 49152;
    int fb = idx2 >> 9;           // ((w*2+T)*4+ks)*2+h
    int h  = fb & 1;
    int t2 = fb >> 1;
    int ks = t2 & 3, T2 = t2 >> 2;
    int T  = T2 & 1, w = T2 >> 1;
    int r  = idx2 & 511;
    int l  = r >> 3, j = r & 7;
    int pr = l & 15;
    int g  = (pr&3)*64 + w*8 + T*4 + (pr>>2);
    int k  = ks*32 + 4*(l>>4) + (j & 3) + 16*(j >> 2);
    float src = (k < 64) ? Wih1[g*64 + k] : Whh1[g*64 + (k - 64)];
    unsigned short hi = f2bf(src);
    Wpk[idx] = h ? f2bf(src - bf2f(hi)) : hi;
  } else {
    int m = idx - 114688;
    if (m < 256) b0[m] = bih0[m] + bhh0[m];
    else if (m < 512) b1[m-256] = bih1[m-256] + bhh1[m-256];
  }
}

// ---------------- CSR build (dst-indexed) ----------------
__global__ void count_deg(const int* __restrict__ ei, int* __restrict__ deg){
  int e = blockIdx.x*256 + threadIdx.x;
  if (e >= ETOT) return;
  int s, d; edge_sd(ei, e, s, d);
  atomicAdd(deg + d, 1);
}

__global__ void scan_deg(const int* __restrict__ deg, int* __restrict__ indptr, int* __restrict__ cursor){
  __shared__ int part[256];
  const int t = threadIdx.x;
  const int CH = (NN + 255) / 256;
  const int c0 = t * CH;
  int sum = 0;
  for (int i=0;i<CH;i++){ int idx=c0+i; if (idx<NN) sum += deg[idx]; }
  part[t] = sum; __syncthreads();
  int val = sum;
  for (int off=1; off<256; off<<=1){
    int add = (t>=off) ? part[t-off] : 0;
    __syncthreads();
    val += add; part[t] = val;
    __syncthreads();
  }
  int run = val - sum;
  for (int i=0;i<CH;i++){
    int idx=c0+i;
    if (idx<NN){ indptr[idx]=run; cursor[idx]=run; run += deg[idx]; }
  }
  if (t == 0) indptr[NN] = ETOT;
}

__global__ void scatter_edges(const int* __restrict__ ei, int* __restrict__ cursor, int* __restrict__ csr_src){
  int e = blockIdx.x*256 + threadIdx.x;
  if (e >= ETOT) return;
  int s, d; edge_sd(ei, e, s, d);
  int pos = atomicAdd(cursor + d, 1);
  csr_src[pos] = s;
}

// pin a 16B weight fragment into VGPRs: opaque to compiler -> cannot be rematerialized
#define PIN_LOAD(dst, p) asm volatile( \
    "global_load_dwordx4 %0, %1, off\n\t" \
    "s_waitcnt vmcnt(0)" \
    : "=&v"(dst) : "v"(p))

// ---------------- MFMA split-bf16 2-layer LSTM: 8 waves, weights register-resident ----------------
__global__ __launch_bounds__(512, 2)
__attribute__((amdgpu_waves_per_eu(2, 2)))
void lstm_mfma(
    const float* __restrict__ x,
    const unsigned short* __restrict__ Wpk,
    const float* __restrict__ b0, const float* __restrict__ b1,
    float* __restrict__ h1out)
{
  __shared__ unsigned short Zh[NB*ZROW];   // 26.2 KB
  __shared__ unsigned short Zl[NB*ZROW];   // 26.2 KB

  const int tid  = threadIdx.x;
  const int lane = tid & 63;
  const int w    = __builtin_amdgcn_readfirstlane(tid >> 6);   // 0..7
  const int ln15 = lane & 15;
  const int lq   = lane >> 4;                                  // 0..3
  const int gbase = blockIdx.x * NB;

  const bf16x8* wp = (const bf16x8*)Wpk;

  // ---- pin all 28 weight fragments in registers (112 VGPRs, loaded once) ----
  bf16x8 wA0h[2][3], wA0l[2][3], wA1h[2][4], wA1l[2][4];
#pragma unroll
  for (int T=0; T<2; ++T){
#pragma unroll
    for (int ks=0; ks<3; ++ks){
      PIN_LOAD(wA0h[T][ks], wp + (((w*2+T)*3+ks)*2+0)*64 + lane);
      PIN_LOAD(wA0l[T][ks], wp + (((w*2+T)*3+ks)*2+1)*64 + lane);
    }
#pragma unroll
    for (int ks=0; ks<4; ++ks){
      PIN_LOAD(wA1h[T][ks], wp + 6144 + (((w*2+T)*4+ks)*2+0)*64 + lane);
      PIN_LOAD(wA1l[T][ks], wp + 6144 + (((w*2+T)*4+ks)*2+1)*64 + lane);
    }
  }

  // bias per lane: bv[T][j] = b[j*64 + w*8 + T*4 + lq]
  f32x4 bv0[2], bv1[2];
#pragma unroll
  for (int T=0; T<2; ++T){
    const int u = w*8 + T*4 + lq;
#pragma unroll
    for (int j=0; j<4; ++j){ bv0[T][j] = b0[j*64+u]; bv1[T][j] = b1[j*64+u]; }
  }

  // x staging: quads q1=tid, q2=512+tid (tid<128); node=q>>3, k=(q&7)*4
  const int xn1 = tid >> 3,        xk1 = (tid & 7)*4;
  const int xn2 = (512+tid) >> 3,  xk2 = ((512+tid) & 7)*4;
  const float* xp1 = x + (size_t)(gbase + xn1)*(TT*INF_) + xk1;
  const float* xp2 = x + (size_t)(gbase + xn2)*(TT*INF_) + xk2;
  const bool x2 = (tid < 128);

  // ---- prologue: zero Z, stage x(0) ----
  for (int i = tid; i < NB*ZROW/2; i += 512){ ((unsigned*)Zh)[i] = 0; ((unsigned*)Zl)[i] = 0; }
  __syncthreads();
  {
    float4 v = *(const float4*)xp1;
    unsigned short h_[4], l_[4];
    h_[0]=f2bf(v.x); h_[1]=f2bf(v.y); h_[2]=f2bf(v.z); h_[3]=f2bf(v.w);
    l_[0]=f2bf(v.x-bf2f(h_[0])); l_[1]=f2bf(v.y-bf2f(h_[1]));
    l_[2]=f2bf(v.z-bf2f(h_[2])); l_[3]=f2bf(v.w-bf2f(h_[3]));
    *(uint2*)&Zh[xn1*ZROW + xk1] = make_uint2((unsigned)h_[0]|((unsigned)h_[1]<<16),(unsigned)h_[2]|((unsigned)h_[3]<<16));
    *(uint2*)&Zl[xn1*ZROW + xk1] = make_uint2((unsigned)l_[0]|((unsigned)l_[1]<<16),(unsigned)l_[2]|((unsigned)l_[3]<<16));
    if (x2){
      float4 u = *(const float4*)xp2;
      h_[0]=f2bf(u.x); h_[1]=f2bf(u.y); h_[2]=f2bf(u.z); h_[3]=f2bf(u.w);
      l_[0]=f2bf(u.x-bf2f(h_[0])); l_[1]=f2bf(u.y-bf2f(h_[1]));
      l_[2]=f2bf(u.z-bf2f(h_[2])); l_[3]=f2bf(u.w-bf2f(h_[3]));
      *(uint2*)&Zh[xn2*ZROW + xk2] = make_uint2((unsigned)h_[0]|((unsigned)h_[1]<<16),(unsigned)h_[2]|((unsigned)h_[3]<<16));
      *(uint2*)&Zl[xn2*ZROW + xk2] = make_uint2((unsigned)l_[0]|((unsigned)l_[1]<<16),(unsigned)l_[2]|((unsigned)l_[3]<<16));
    }
  }
  __syncthreads();

  float c0[10], c1[10];   // [T*5+GG]
#pragma unroll
  for (int i=0;i<10;i++){ c0[i]=0.f; c1[i]=0.f; }
  f32x4 aL1[2][5];

#define ZFRAG(Zb, node, kz) ({                                            \
    const unsigned short* _p = &Zb[(node)*ZROW + (kz) + 4*lq];            \
    short4v _a = *(const short4v*)_p;                                     \
    short4v _b = *(const short4v*)(_p + 16);                              \
    __builtin_shufflevector(_a, _b, 0,1,2,3,4,5,6,7); })

#define MF(acc, A, B) acc = __builtin_amdgcn_mfma_f32_16x16x32_bf16((A),(B),(acc),0,0,0)

#define HWRITE(hv, col) {                                                 \
    const unsigned short _hh = f2bf(hv);                                  \
    Zh[_n*ZROW + (col)] = _hh;                                            \
    Zl[_n*ZROW + (col)] = f2bf((hv) - bf2f(_hh)); }

  for (int t=0; t<TT; ++t){
    // ====== P1: issue x(t+1) loads; L1-pointwise(t-1) -> H1 (aL1 dies); L0 MFMA (aL0 born) ======
    float4 xv1, xv2;
    const bool dox = (t+1 < TT);
    if (dox){ xv1 = *(const float4*)(xp1 + (size_t)(t+1)*INF_);
              if (x2) xv2 = *(const float4*)(xp2 + (size_t)(t+1)*INF_); }

    if (t > 0){
#pragma unroll
      for (int T=0; T<2; ++T){
        const int uc = 96 + w*8 + T*4 + lq;
#pragma unroll
        for (int GG=0; GG<5; ++GG){
          const int _n = GG*16 + ln15;
          float h = lstm_cell(aL1[T][GG][0], aL1[T][GG][1], aL1[T][GG][2], aL1[T][GG][3], c1[T*5+GG]);
          HWRITE(h, uc);
        }
      }
    }

    f32x4 aL0[2][5];
#pragma unroll
    for (int T=0; T<2; ++T)
#pragma unroll
      for (int GG=0; GG<5; ++GG) aL0[T][GG] = bv0[T];

#pragma unroll
    for (int ks=0; ks<3; ++ks){
      const int kz = ks*32;
#pragma unroll
      for (int GG=0; GG<5; ++GG){
        const bf16x8 zh = ZFRAG(Zh, GG*16+ln15, kz);
        const bf16x8 zl = ZFRAG(Zl, GG*16+ln15, kz);
        MF(aL0[0][GG], wA0h[0][ks], zh); MF(aL0[0][GG], wA0h[0][ks], zl); MF(aL0[0][GG], wA0l[0][ks], zh);
        MF(aL0[1][GG], wA0h[1][ks], zh); MF(aL0[1][GG], wA0h[1][ks], zl); MF(aL0[1][GG], wA0l[1][ks], zh);
      }
    }
    __syncthreads();

    // ====== P2: L0-pointwise -> H0 + x(t+1) write (aL0 dies); then L1 MFMA slabs 2,3 (aL1 born) ======
#pragma unroll
    for (int T=0; T<2; ++T){
      const int uc = 32 + w*8 + T*4 + lq;
#pragma unroll
      for (int GG=0; GG<5; ++GG){
        const int _n = GG*16 + ln15;
        float h = lstm_cell(aL0[T][GG][0], aL0[T][GG][1], aL0[T][GG][2], aL0[T][GG][3], c0[T*5+GG]);
        HWRITE(h, uc);
      }
    }
    if (dox){
      unsigned short h_[4], l_[4];
      h_[0]=f2bf(xv1.x); h_[1]=f2bf(xv1.y); h_[2]=f2bf(xv1.z); h_[3]=f2bf(xv1.w);
      l_[0]=f2bf(xv1.x-bf2f(h_[0])); l_[1]=f2bf(xv1.y-bf2f(h_[1]));
      l_[2]=f2bf(xv1.z-bf2f(h_[2])); l_[3]=f2bf(xv1.w-bf2f(h_[3]));
      *(uint2*)&Zh[xn1*ZROW + xk1] = make_uint2((unsigned)h_[0]|((unsigned)h_[1]<<16),(unsigned)h_[2]|((unsigned)h_[3]<<16));
      *(uint2*)&Zl[xn1*ZROW + xk1] = make_uint2((unsigned)l_[0]|((unsigned)l_[1]<<16),(unsigned)l_[2]|((unsigned)l_[3]<<16));
      if (x2){
        h_[0]=f2bf(xv2.x); h_[1]=f2bf(xv2.y); h_[2]=f2bf(xv2.z); h_[3]=f2bf(xv2.w);
        l_[0]=f2bf(xv2.x-bf2f(h_[0])); l_[1]=f2bf(xv2.y-bf2f(h_[1]));
        l_[2]=f2bf(xv2.z-bf2f(h_[2])); l_[3]=f2bf(xv2.w-bf2f(h_[3]));
        *(uint2*)&Zh[xn2*ZROW + xk2] = make_uint2((unsigned)h_[0]|((unsigned)h_[1]<<16),(unsigned)h_[2]|((unsigned)h_[3]<<16));
        *(uint2*)&Zl[xn2*ZROW + xk2] = make_uint2((unsigned)l_[0]|((unsigned)l_[1]<<16),(unsigned)l_[2]|((unsigned)l_[3]<<16));
      }
    }

#pragma unroll
    for (int T=0; T<2; ++T)
#pragma unroll
      for (int GG=0; GG<5; ++GG) aL1[T][GG] = bv1[T];

#pragma unroll
    for (int ks=2; ks<4; ++ks){
      const int kz = 32 + ks*32;   // 96, 128 (h1 slabs)
#pragma unroll
      for (int GG=0; GG<5; ++GG){
        const bf16x8 zh = ZFRAG(Zh, GG*16+ln15, kz);
        const bf16x8 zl = ZFRAG(Zl, GG*16+ln15, kz);
        MF(aL1[0][GG], wA1h[0][ks], zh); MF(aL1[0][GG], wA1h[0][ks], zl); MF(aL1[0][GG], wA1l[0][ks], zh);
        MF(aL1[1][GG], wA1h[1][ks], zh); MF(aL1[1][GG], wA1h[1][ks], zl); MF(aL1[1][GG], wA1l[1][ks], zh);
      }
    }
    __syncthreads();

    // ====== P3: L1 MFMA slabs 0,1 (reads H0 just written) ======
#pragma unroll
    for (int ks=0; ks<2; ++ks){
      const int kz = 32 + ks*32;   // 32, 64 (h0 slabs)
#pragma unroll
      for (int GG=0; GG<5; ++GG){
        const bf16x8 zh = ZFRAG(Zh, GG*16+ln15, kz);
        const bf16x8 zl = ZFRAG(Zl, GG*16+ln15, kz);
        MF(aL1[0][GG], wA1h[0][ks], zh); MF(aL1[0][GG], wA1h[0][ks], zl); MF(aL1[0][GG], wA1l[0][ks], zh);
        MF(aL1[1][GG], wA1h[1][ks], zh); MF(aL1[1][GG], wA1h[1][ks], zl); MF(aL1[1][GG], wA1l[1][ks], zh);
      }
    }
    __syncthreads();
  }

  // final L1 pointwise -> H1
#pragma unroll
  for (int T=0; T<2; ++T){
    const int uc = 96 + w*8 + T*4 + lq;
#pragma unroll
    for (int GG=0; GG<5; ++GG){
      const int _n = GG*16 + ln15;
      float h = lstm_cell(aL1[T][GG][0], aL1[T][GG][1], aL1[T][GG][2], aL1[T][GG][3], c1[T*5+GG]);
      HWRITE(h, uc);
    }
  }
  __syncthreads();

  // epilogue: coalesced h1 write
  for (int o = tid; o < NB*64; o += 512){
    const int n = o >> 6, u = o & 63;
    h1out[(size_t)(gbase+n)*64 + u] = bf2f(Zh[n*ZROW + 96 + u]) + bf2f(Zl[n*ZROW + 96 + u]);
  }
#undef ZFRAG
#undef MF
#undef HWRITE
}

// ---------------- GAT layer 1 prep: 8 nodes/block (amortize W reads) ----------------
__global__ __launch_bounds__(256) void gat1_prep(const float* __restrict__ h1, const float* __restrict__ W,
  const float* __restrict__ as_, const float* __restrict__ ad_,
  float* __restrict__ xh, float* __restrict__ als, float* __restrict__ ald)
{
  __shared__ float hs[8][64];
  const int nb0 = blockIdx.x * 8;
  const int o  = threadIdx.x;
  const int q  = o >> 6, u = o & 63;
  // stage 8x64 h1 tile
  for (int i = o; i < 512; i += 256){
    hs[i>>6][i&63] = h1[(size_t)(nb0 + (i>>6))*64 + (i&63)];
  }
  __syncthreads();
  float acc[8];
#pragma unroll
  for (int nd=0; nd<8; ++nd) acc[nd] = 0.f;
  for (int k=0; k<64; ++k){
    const float wv = W[k*256 + o];
#pragma unroll
    for (int nd=0; nd<8; ++nd) acc[nd] = fmaf(hs[nd][k], wv, acc[nd]);
  }
  const float asv = as_[o], adv = ad_[o];
#pragma unroll
  for (int nd=0; nd<8; ++nd){
    xh[(size_t)(nb0+nd)*256 + o] = acc[nd];
    float ps = acc[nd] * asv;
    float pd = acc[nd] * adv;
#pragma unroll
    for (int off=32; off>=1; off>>=1){ ps += __shfl_xor(ps, off); pd += __shfl_xor(pd, off); }
    if (u == 0){ als[(nb0+nd)*4 + q] = ps; ald[(nb0+nd)*4 + q] = pd; }
  }
}

// ---------------- GAT1 gather + fused epilogue ----------------
__global__ __launch_bounds__(256) void gat1_gather(
  const int* __restrict__ indptr, const int* __restrict__ csr_src,
  const float* __restrict__ als, const float* __restrict__ ald,
  const float* __restrict__ xh,  const float* __restrict__ b1g,
  const float* __restrict__ w2,  const float* __restrict__ as2, const float* __restrict__ ad2,
  float* __restrict__ xh2, float* __restrict__ a2s, float* __restrict__ a2d)
{
  const int d = blockIdx.x*4 + (threadIdx.x >> 6);
  const int lane = threadIdx.x & 63;
  if (d >= NN) return;
  const int p0 = indptr[d], p1 = indptr[d+1];

  float aldv[4];
#pragma unroll
  for (int q=0;q<4;q++) aldv[q] = ald[d*4+q];

  float mx[4];
#pragma unroll
  for (int q=0;q<4;q++) mx[q] = -3.4e38f;
  for (int e=p0+lane; e<p1; e+=64){
    int s = csr_src[e];
#pragma unroll
    for (int q=0;q<4;q++){
      float ev = lrelu(als[s*4+q] + aldv[q]);
      mx[q] = fmaxf(mx[q], ev);
    }
  }
#pragma unroll
  for (int off=32; off>=1; off>>=1){
#pragma unroll
    for (int q=0;q<4;q++) mx[q] = fmaxf(mx[q], __shfl_xor(mx[q], off));
  }

  const int q = lane >> 4;
  const float mq = mx[q];
  const float aldq = aldv[q];
  float ax=0.f, ay=0.f, az=0.f, aw=0.f, den=0.f;
  int s_next = (p0 < p1) ? csr_src[p0] : 0;
  for (int e=p0; e<p1; ++e){
    const int s = s_next;
    if (e+1 < p1) s_next = csr_src[e+1];
    float ev = lrelu(als[s*4+q] + aldq);
    float ex = __expf(ev - mq);
    den += ex;
    float4 v = *(const float4*)(xh + (size_t)s*256 + lane*4);
    ax = fmaf(ex, v.x, ax); ay = fmaf(ex, v.y, ay);
    az = fmaf(ex, v.z, az); aw = fmaf(ex, v.w, aw);
  }
  const float rr = 1.0f/(den + 1e-16f);
  const int o = lane*4;
  float v0 = ax*rr + b1g[o+0];
  float v1 = ay*rr + b1g[o+1];
  float v2 = az*rr + b1g[o+2];
  float v3 = aw*rr + b1g[o+3];
  v0 = v0>0.f?v0:0.f; v1 = v1>0.f?v1:0.f; v2 = v2>0.f?v2:0.f; v3 = v3>0.f?v3:0.f;
  float part = v0*w2[o+0] + v1*w2[o+1] + v2*w2[o+2] + v3*w2[o+3];
#pragma unroll
  for (int off=32; off>=1; off>>=1) part += __shfl_xor(part, off);
  if (lane == 0){
    xh2[d] = part;
    a2s[d] = part * as2[0];
    a2d[d] = part * ad2[0];
  }
}

// ---------------- GAT2 gather ----------------
__global__ __launch_bounds__(256) void gat2_gather(
  const int* __restrict__ indptr, const int* __restrict__ csr_src,
  const float* __restrict__ a2s, const float* __restrict__ a2d,
  const float* __restrict__ xh2, const float* __restrict__ b2,
  float* __restrict__ out)
{
  const int d = blockIdx.x*4 + (threadIdx.x >> 6);
  const int lane = threadIdx.x & 63;
  if (d >= NN) return;
  const int p0 = indptr[d], p1 = indptr[d+1];
  const float add = a2d[d];

  float mx = -3.4e38f;
  for (int e=p0+lane; e<p1; e+=64){
    int s = csr_src[e];
    mx = fmaxf(mx, lrelu(a2s[s] + add));
  }
#pragma unroll
  for (int off=32; off>=1; off>>=1) mx = fmaxf(mx, __shfl_xor(mx, off));

  float den = 0.f, num = 0.f;
  for (int e=p0+lane; e<p1; e+=64){
    int s = csr_src[e];
    float ev = lrelu(a2s[s] + add);
    float ex = __expf(ev - mx);
    den += ex;
    num = fmaf(ex, xh2[s], num);
  }
#pragma unroll
  for (int off=32; off>=1; off>>=1){ den += __shfl_xor(den, off); num += __shfl_xor(num, off); }
  if (lane == 0) out[d] = num/(den + 1e-16f) + b2[0];
}

// ---------------- launcher ----------------
extern "C" void kernel_launch(void* const* d_in, const int* in_sizes, int n_in,
                              void* d_out, int out_size, void* d_ws, size_t ws_size,
                              hipStream_t stream)
{
  const float* x    = (const float*)d_in[0];
  const int*   ei   = (const int*)d_in[1];
  const float* Wih0 = (const float*)d_in[2];
  const float* Whh0 = (const float*)d_in[3];
  const float* bih0 = (const float*)d_in[4];
  const float* bhh0 = (const float*)d_in[5];
  const float* Wih1 = (const float*)d_in[6];
  const float* Whh1 = (const float*)d_in[7];
  const float* bih1 = (const float*)d_in[8];
  const float* bhh1 = (const float*)d_in[9];
  const float* g1w  = (const float*)d_in[10];
  const float* g1as = (const float*)d_in[11];
  const float* g1ad = (const float*)d_in[12];
  const float* g1b  = (const float*)d_in[13];
  const float* g2w  = (const float*)d_in[14];
  const float* g2as = (const float*)d_in[15];
  const float* g2ad = (const float*)d_in[16];
  const float* g2b  = (const float*)d_in[17];

  float* ws  = (float*)d_ws;
  unsigned short* Wpk = (unsigned short*)ws;   // 114688 shorts = 57344 f32 slots
  float* b0  = ws + 57344;            // 256
  float* b1  = b0 + 256;              // 256
  float* h1  = b1 + 256;              // 20000*64
  float* xh  = h1 + 1280000;          // 20000*256
  float* als = xh + 5120000;          // 80000
  float* ald = als + 80000;           // 80000
  float* xh2 = ald + 80000;           // 20000
  float* a2s = xh2 + 20000;           // 20000
  float* a2d = a2s + 20000;           // 20000
  int*   deg    = (int*)(a2d + 20000);   // 20000
  int*   indptr = deg + 20000;           // 20001
  int*   cursor = indptr + 20001;        // 20000
  int*   csr    = cursor + 20000;        // 340000

  kzero_int<<<(NN+255)/256, 256, 0, stream>>>(deg, NN);
  pack_weights<<<450, 256, 0, stream>>>(Wih0,Whh0,bih0,bhh0,Wih1,Whh1,bih1,bhh1,Wpk,b0,b1);
  count_deg<<<(ETOT+255)/256, 256, 0, stream>>>(ei, deg);
  scan_deg<<<1, 256, 0, stream>>>(deg, indptr, cursor);
  scatter_edges<<<(ETOT+255)/256, 256, 0, stream>>>(ei, cursor, csr);
  lstm_mfma<<<250, 512, 0, stream>>>(x, Wpk, b0, b1, h1);
  gat1_prep<<<NN/8, 256, 0, stream>>>(h1, g1w, g1as, g1ad, xh, als, ald);
  gat1_gather<<<(NN+3)/4, 256, 0, stream>>>(indptr, csr, als, ald, xh, g1b, g2w, g2as, g2ad, xh2, a2s, a2d);
  gat2_gather<<<(NN+3)/4, 256, 0, stream>>>(indptr, csr, a2s, a2d, xh2, g2b, (float*)d_out);
}

// Round 10
// 412.868 us; speedup vs baseline: 1.7950x; 1.0196x over previous
//
#include <hip/hip_runtime.h>
#include <math.h>

#define NN   20000
#define TT   32
#define INF_ 32
#define HID  64
#define NH   4
#define EE   320000
#define ETOT (EE + NN)
#define ZROW 164   // shorts/row: 160 data + 4 pad; node stride 41x8B-units (odd) -> b64 conflict-free
#define NB   80    // nodes per LSTM block; 250*80 = 20000 exact

typedef __attribute__((ext_vector_type(8))) short bf16x8;
typedef __attribute__((ext_vector_type(4))) short short4v;
typedef __attribute__((ext_vector_type(4))) float f32x4;

static __device__ __forceinline__ float lrelu(float x){ return x>0.0f ? x : 0.2f*x; }

static __device__ __forceinline__ unsigned short f2bf(float f){
  unsigned u = __float_as_uint(f);
  unsigned r = u + 0x7fffu + ((u>>16)&1u);
  return (unsigned short)(r>>16);
}
static __device__ __forceinline__ float bf2f(unsigned short h){ return __uint_as_float(((unsigned)h)<<16); }

// fused LSTM cell: 5 exp + 2 rcp
static __device__ __forceinline__ float lstm_cell(float gi, float gf, float gg, float go, float& c){
  float ef = __expf(-gf), ei = __expf(-gi), eg = __expf(-2.0f*gg);
  float pN = c*(1.0f+ei)*(1.0f+eg) + (1.0f-eg)*(1.0f+ef);
  float pD = (1.0f+ef)*(1.0f+ei)*(1.0f+eg);
  float cc = pN * __builtin_amdgcn_rcpf(pD);
  c = cc;
  float eo = __expf(-go), ec = __expf(-2.0f*cc);
  return (1.0f-ec) * __builtin_amdgcn_rcpf((1.0f+eo)*(1.0f+ec));
}

static __device__ __forceinline__ void edge_sd(const int* __restrict__ ei, int e, int& s, int& d){
  if (e < EE){ s = ei[e]; d = ei[EE + e]; } else { s = e - EE; d = s; }
}

// ---------------- utility kernels ----------------
__global__ void kzero_int(int* __restrict__ p, int n){
  int i = blockIdx.x*256 + threadIdx.x;
  if (i < n) p[i] = 0;
}

// Pack weights into MFMA A-frag layout, rows permuted so C/D row = 4*unitLocal + gateType.
// tile index tl = 0..15 (one per wave). g = (pr&3)*64 + tl*4 + (pr>>2). (same data as R7/R8)
__global__ void pack_weights(const float* __restrict__ Wih0, const float* __restrict__ Whh0,
                             const float* __restrict__ bih0, const float* __restrict__ bhh0,
                             const float* __restrict__ Wih1, const float* __restrict__ Whh1,
                             const float* __restrict__ bih1, const float* __restrict__ bhh1,
                             unsigned short* __restrict__ Wpk,
                             float* __restrict__ b0, float* __restrict__ b1){
  int idx = blockIdx.x*256 + threadIdx.x;
  if (idx < 49152){
    int fb = idx >> 9;            // (tl*3+ks)*2+h
    int h  = fb & 1;
    int t2 = fb >> 1;
    int ks = t2 % 3, tl = t2 / 3;
    int r  = idx & 511;
    int l  = r >> 3, j = r & 7;
    int pr = l & 15;
    int g  = (pr&3)*64 + tl*4 + (pr>>2);
    int k  = ks*32 + 4*(l>>4) + (j & 3) + 16*(j >> 2);
    float src = (k < 32) ? Wih0[g*32 + k] : Whh0[g*64 + (k - 32)];
    unsigned short hi = f2bf(src);
    Wpk[idx] = h ? f2bf(src - bf2f(hi)) : hi;
  } else if (idx < 114688){
    int idx2 = idx - 49152;
    int fb = idx2 >> 9;           // (tl*4+ks)*2+h
    int h  = fb & 1;
    int t2 = fb >> 1;
    int ks = t2 & 3, tl = t2 >> 2;
    int r  = idx2 & 511;
    int l  = r >> 3, j = r & 7;
    int pr = l & 15;
    int g  = (pr&3)*64 + tl*4 + (pr>>2);
    int k  = ks*32 + 4*(l>>4) + (j & 3) + 16*(j >> 2);
    float src = (k < 64) ? Wih1[g*64 + k] : Whh1[g*64 + (k - 64)];
    unsigned short hi = f2bf(src);
    Wpk[idx] = h ? f2bf(src - bf2f(hi)) : hi;
  } else {
    int m = idx - 114688;
    if (m < 256) b0[m] = bih0[m] + bhh0[m];
    else if (m < 512) b1[m-256] = bih1[m-256] + bhh1[m-256];
  }
}

// ---------------- CSR build (dst-indexed) ----------------
__global__ void count_deg(const int* __restrict__ ei, int* __restrict__ deg){
  int e = blockIdx.x*256 + threadIdx.x;
  if (e >= ETOT) return;
  int s, d; edge_sd(ei, e, s, d);
  atomicAdd(deg + d, 1);
}

__global__ void scan_deg(const int* __restrict__ deg, int* __restrict__ indptr, int* __restrict__ cursor){
  __shared__ int part[256];
  const int t = threadIdx.x;
  const int CH = (NN + 255) / 256;
  const int c0 = t * CH;
  int sum = 0;
  for (int i=0;i<CH;i++){ int idx=c0+i; if (idx<NN) sum += deg[idx]; }
  part[t] = sum; __syncthreads();
  int val = sum;
  for (int off=1; off<256; off<<=1){
    int add = (t>=off) ? part[t-off] : 0;
    __syncthreads();
    val += add; part[t] = val;
    __syncthreads();
  }
  int run = val - sum;
  for (int i=0;i<CH;i++){
    int idx=c0+i;
    if (idx<NN){ indptr[idx]=run; cursor[idx]=run; run += deg[idx]; }
  }
  if (t == 0) indptr[NN] = ETOT;
}

__global__ void scatter_edges(const int* __restrict__ ei, int* __restrict__ cursor, int* __restrict__ csr_src){
  int e = blockIdx.x*256 + threadIdx.x;
  if (e >= ETOT) return;
  int s, d; edge_sd(ei, e, s, d);
  int pos = atomicAdd(cursor + d, 1);
  csr_src[pos] = s;
}

// pin a 16B weight fragment into VGPRs: opaque to compiler -> cannot be rematerialized
#define PIN_LOAD(dst, p) asm volatile( \
    "global_load_dwordx4 %0, %1, off\n\t" \
    "s_waitcnt vmcnt(0)" \
    : "=&v"(dst) : "v"(p))

// ---------------- MFMA split-bf16 2-layer LSTM: 16 waves, 4 waves/SIMD ----------------
// Wave w owns units w*4..w*4+3 (one 16-row tile: 4 units x 4 gates). 14 weight frags
// register-resident (56 VGPR). In-register pointwise. 3 barriers/t.
__global__ __launch_bounds__(1024)
__attribute__((amdgpu_waves_per_eu(4, 4)))
void lstm_mfma(
    const float* __restrict__ x,
    const unsigned short* __restrict__ Wpk,
    const float* __restrict__ b0, const float* __restrict__ b1,
    float* __restrict__ h1out)
{
  __shared__ unsigned short Zh[NB*ZROW];   // 26.2 KB
  __shared__ unsigned short Zl[NB*ZROW];   // 26.2 KB

  const int tid  = threadIdx.x;
  const int lane = tid & 63;
  const int w    = __builtin_amdgcn_readfirstlane(tid >> 6);   // 0..15
  const int ln15 = lane & 15;
  const int lq   = lane >> 4;                                  // 0..3
  const int gbase = blockIdx.x * NB;

  const bf16x8* wp = (const bf16x8*)Wpk;

  // ---- pin 14 weight fragments in registers (56 VGPRs) ----
  bf16x8 wA0h[3], wA0l[3], wA1h[4], wA1l[4];
#pragma unroll
  for (int ks=0; ks<3; ++ks){
    PIN_LOAD(wA0h[ks], wp + ((w*3+ks)*2+0)*64 + lane);
    PIN_LOAD(wA0l[ks], wp + ((w*3+ks)*2+1)*64 + lane);
  }
#pragma unroll
  for (int ks=0; ks<4; ++ks){
    PIN_LOAD(wA1h[ks], wp + 6144 + ((w*4+ks)*2+0)*64 + lane);
    PIN_LOAD(wA1l[ks], wp + 6144 + ((w*4+ks)*2+1)*64 + lane);
  }

  // bias per lane: bv[j] = b[j*64 + w*4 + lq]
  f32x4 bv0, bv1;
  {
    const int u = w*4 + lq;
#pragma unroll
    for (int j=0; j<4; ++j){ bv0[j] = b0[j*64+u]; bv1[j] = b1[j*64+u]; }
  }

  // x staging: threads 0..639, one quad each: node xn=tid>>3, k=(tid&7)*4
  const int xn = tid >> 3;
  const int xk = (tid & 7) * 4;
  const float* xp = x + (size_t)(gbase + ((xn < NB) ? xn : 0))*(TT*INF_) + xk;
  const bool xth = (tid < 640);

  // ---- prologue: zero Z, stage x(0) ----
  for (int i = tid; i < NB*ZROW/2; i += 1024){ ((unsigned*)Zh)[i] = 0; ((unsigned*)Zl)[i] = 0; }
  __syncthreads();
  if (xth){
    float4 v = *(const float4*)xp;
    unsigned short h_[4], l_[4];
    h_[0]=f2bf(v.x); h_[1]=f2bf(v.y); h_[2]=f2bf(v.z); h_[3]=f2bf(v.w);
    l_[0]=f2bf(v.x-bf2f(h_[0])); l_[1]=f2bf(v.y-bf2f(h_[1]));
    l_[2]=f2bf(v.z-bf2f(h_[2])); l_[3]=f2bf(v.w-bf2f(h_[3]));
    *(uint2*)&Zh[xn*ZROW + xk] = make_uint2((unsigned)h_[0]|((unsigned)h_[1]<<16),(unsigned)h_[2]|((unsigned)h_[3]<<16));
    *(uint2*)&Zl[xn*ZROW + xk] = make_uint2((unsigned)l_[0]|((unsigned)l_[1]<<16),(unsigned)l_[2]|((unsigned)l_[3]<<16));
  }
  __syncthreads();

  float c0[5], c1[5];
#pragma unroll
  for (int i=0;i<5;i++){ c0[i]=0.f; c1[i]=0.f; }
  f32x4 aL1[5];

#define ZFRAG(Zb, node, kz) ({                                            \
    const unsigned short* _p = &Zb[(node)*ZROW + (kz) + 4*lq];            \
    short4v _a = *(const short4v*)_p;                                     \
    short4v _b = *(const short4v*)(_p + 16);                              \
    __builtin_shufflevector(_a, _b, 0,1,2,3,4,5,6,7); })

#define MF(acc, A, B) acc = __builtin_amdgcn_mfma_f32_16x16x32_bf16((A),(B),(acc),0,0,0)

#define HWRITE(hv, col) {                                                 \
    const unsigned short _hh = f2bf(hv);                                  \
    Zh[_n*ZROW + (col)] = _hh;                                            \
    Zl[_n*ZROW + (col)] = f2bf((hv) - bf2f(_hh)); }

  for (int t=0; t<TT; ++t){
    // ====== P1: issue x(t+1) load; L1-pointwise(t-1) -> H1 (aL1 dies); L0 MFMA (aL0 born) ======
    float4 xv;
    const bool dox = xth && (t+1 < TT);
    if (dox) xv = *(const float4*)(xp + (size_t)(t+1)*INF_);

    if (t > 0){
      const int uc = 96 + w*4 + lq;
#pragma unroll
      for (int GG=0; GG<5; ++GG){
        const int _n = GG*16 + ln15;
        float h = lstm_cell(aL1[GG][0], aL1[GG][1], aL1[GG][2], aL1[GG][3], c1[GG]);
        HWRITE(h, uc);
      }
    }

    f32x4 aL0[5];
#pragma unroll
    for (int GG=0; GG<5; ++GG) aL0[GG] = bv0;

#pragma unroll
    for (int ks=0; ks<3; ++ks){
      const int kz = ks*32;
#pragma unroll
      for (int GG=0; GG<5; ++GG){
        const bf16x8 zh = ZFRAG(Zh, GG*16+ln15, kz);
        const bf16x8 zl = ZFRAG(Zl, GG*16+ln15, kz);
        MF(aL0[GG], wA0h[ks], zh); MF(aL0[GG], wA0h[ks], zl); MF(aL0[GG], wA0l[ks], zh);
      }
    }
    __syncthreads();

    // ====== P2: L0-pointwise -> H0 + x(t+1) write (aL0 dies); L1 MFMA slabs 2,3 (aL1 born) ======
    {
      const int uc = 32 + w*4 + lq;
#pragma unroll
      for (int GG=0; GG<5; ++GG){
        const int _n = GG*16 + ln15;
        float h = lstm_cell(aL0[GG][0], aL0[GG][1], aL0[GG][2], aL0[GG][3], c0[GG]);
        HWRITE(h, uc);
      }
    }
    if (dox){
      unsigned short h_[4], l_[4];
      h_[0]=f2bf(xv.x); h_[1]=f2bf(xv.y); h_[2]=f2bf(xv.z); h_[3]=f2bf(xv.w);
      l_[0]=f2bf(xv.x-bf2f(h_[0])); l_[1]=f2bf(xv.y-bf2f(h_[1]));
      l_[2]=f2bf(xv.z-bf2f(h_[2])); l_[3]=f2bf(xv.w-bf2f(h_[3]));
      *(uint2*)&Zh[xn*ZROW + xk] = make_uint2((unsigned)h_[0]|((unsigned)h_[1]<<16),(unsigned)h_[2]|((unsigned)h_[3]<<16));
      *(uint2*)&Zl[xn*ZROW + xk] = make_uint2((unsigned)l_[0]|((unsigned)l_[1]<<16),(unsigned)l_[2]|((unsigned)l_[3]<<16));
    }

#pragma unroll
    for (int GG=0; GG<5; ++GG) aL1[GG] = bv1;

#pragma unroll
    for (int ks=2; ks<4; ++ks){
      const int kz = 32 + ks*32;   // 96, 128 (h1 slabs)
#pragma unroll
      for (int GG=0; GG<5; ++GG){
        const bf16x8 zh = ZFRAG(Zh, GG*16+ln15, kz);
        const bf16x8 zl = ZFRAG(Zl, GG*16+ln15, kz);
        MF(aL1[GG], wA1h[ks], zh); MF(aL1[GG], wA1h[ks], zl); MF(aL1[GG], wA1l[ks], zh);
      }
    }
    __syncthreads();

    // ====== P3: L1 MFMA slabs 0,1 (reads H0 just written) ======
#pragma unroll
    for (int ks=0; ks<2; ++ks){
      const int kz = 32 + ks*32;   // 32, 64 (h0 slabs)
#pragma unroll
      for (int GG=0; GG<5; ++GG){
        const bf16x8 zh = ZFRAG(Zh, GG*16+ln15, kz);
        const bf16x8 zl = ZFRAG(Zl, GG*16+ln15, kz);
        MF(aL1[GG], wA1h[ks], zh); MF(aL1[GG], wA1h[ks], zl); MF(aL1[GG], wA1l[ks], zh);
      }
    }
    __syncthreads();
  }

  // final L1 pointwise -> H1
  {
    const int uc = 96 + w*4 + lq;
#pragma unroll
    for (int GG=0; GG<5; ++GG){
      const int _n = GG*16 + ln15;
      float h = lstm_cell(aL1[GG][0], aL1[GG][1], aL1[GG][2], aL1[GG][3], c1[GG]);
      HWRITE(h, uc);
    }
  }
  __syncthreads();

  // epilogue: coalesced h1 write
  for (int o = tid; o < NB*64; o += 1024){
    const int n = o >> 6, u = o & 63;
    h1out[(size_t)(gbase+n)*64 + u] = bf2f(Zh[n*ZROW + 96 + u]) + bf2f(Zl[n*ZROW + 96 + u]);
  }
#undef ZFRAG
#undef MF
#undef HWRITE
}

// ---------------- GAT layer 1 prep: 8 nodes/block (amortize W reads) ----------------
__global__ __launch_bounds__(256) void gat1_prep(const float* __restrict__ h1, const float* __restrict__ W,
  const float* __restrict__ as_, const float* __restrict__ ad_,
  float* __restrict__ xh, float* __restrict__ als, float* __restrict__ ald)
{
  __shared__ float hs[8][64];
  const int nb0 = blockIdx.x * 8;
  const int o  = threadIdx.x;
  const int q  = o >> 6, u = o & 63;
  for (int i = o; i < 512; i += 256){
    hs[i>>6][i&63] = h1[(size_t)(nb0 + (i>>6))*64 + (i&63)];
  }
  __syncthreads();
  float acc[8];
#pragma unroll
  for (int nd=0; nd<8; ++nd) acc[nd] = 0.f;
  for (int k=0; k<64; ++k){
    const float wv = W[k*256 + o];
#pragma unroll
    for (int nd=0; nd<8; ++nd) acc[nd] = fmaf(hs[nd][k], wv, acc[nd]);
  }
  const float asv = as_[o], adv = ad_[o];
#pragma unroll
  for (int nd=0; nd<8; ++nd){
    xh[(size_t)(nb0+nd)*256 + o] = acc[nd];
    float ps = acc[nd] * asv;
    float pd = acc[nd] * adv;
#pragma unroll
    for (int off=32; off>=1; off>>=1){ ps += __shfl_xor(ps, off); pd += __shfl_xor(pd, off); }
    if (u == 0){ als[(nb0+nd)*4 + q] = ps; ald[(nb0+nd)*4 + q] = pd; }
  }
}

// ---------------- GAT1 gather + fused epilogue ----------------
__global__ __launch_bounds__(256) void gat1_gather(
  const int* __restrict__ indptr, const int* __restrict__ csr_src,
  const float* __restrict__ als, const float* __restrict__ ald,
  const float* __restrict__ xh,  const float* __restrict__ b1g,
  const float* __restrict__ w2,  const float* __restrict__ as2, const float* __restrict__ ad2,
  float* __restrict__ xh2, float* __restrict__ a2s, float* __restrict__ a2d)
{
  const int d = blockIdx.x*4 + (threadIdx.x >> 6);
  const int lane = threadIdx.x & 63;
  if (d >= NN) return;
  const int p0 = indptr[d], p1 = indptr[d+1];

  float aldv[4];
#pragma unroll
  for (int q=0;q<4;q++) aldv[q] = ald[d*4+q];

  float mx[4];
#pragma unroll
  for (int q=0;q<4;q++) mx[q] = -3.4e38f;
  for (int e=p0+lane; e<p1; e+=64){
    int s = csr_src[e];
#pragma unroll
    for (int q=0;q<4;q++){
      float ev = lrelu(als[s*4+q] + aldv[q]);
      mx[q] = fmaxf(mx[q], ev);
    }
  }
#pragma unroll
  for (int off=32; off>=1; off>>=1){
#pragma unroll
    for (int q=0;q<4;q++) mx[q] = fmaxf(mx[q], __shfl_xor(mx[q], off));
  }

  const int q = lane >> 4;
  const float mq = mx[q];
  const float aldq = aldv[q];
  float ax=0.f, ay=0.f, az=0.f, aw=0.f, den=0.f;
  int s_next = (p0 < p1) ? csr_src[p0] : 0;
  for (int e=p0; e<p1; ++e){
    const int s = s_next;
    if (e+1 < p1) s_next = csr_src[e+1];
    float ev = lrelu(als[s*4+q] + aldq);
    float ex = __expf(ev - mq);
    den += ex;
    float4 v = *(const float4*)(xh + (size_t)s*256 + lane*4);
    ax = fmaf(ex, v.x, ax); ay = fmaf(ex, v.y, ay);
    az = fmaf(ex, v.z, az); aw = fmaf(ex, v.w, aw);
  }
  const float rr = 1.0f/(den + 1e-16f);
  const int o = lane*4;
  float v0 = ax*rr + b1g[o+0];
  float v1 = ay*rr + b1g[o+1];
  float v2 = az*rr + b1g[o+2];
  float v3 = aw*rr + b1g[o+3];
  v0 = v0>0.f?v0:0.f; v1 = v1>0.f?v1:0.f; v2 = v2>0.f?v2:0.f; v3 = v3>0.f?v3:0.f;
  float part = v0*w2[o+0] + v1*w2[o+1] + v2*w2[o+2] + v3*w2[o+3];
#pragma unroll
  for (int off=32; off>=1; off>>=1) part += __shfl_xor(part, off);
  if (lane == 0){
    xh2[d] = part;
    a2s[d] = part * as2[0];
    a2d[d] = part * ad2[0];
  }
}

// ---------------- GAT2 gather ----------------
__global__ __launch_bounds__(256) void gat2_gather(
  const int* __restrict__ indptr, const int* __restrict__ csr_src,
  const float* __restrict__ a2s, const float* __restrict__ a2d,
  const float* __restrict__ xh2, const float* __restrict__ b2,
  float* __restrict__ out)
{
  const int d = blockIdx.x*4 + (threadIdx.x >> 6);
  const int lane = threadIdx.x & 63;
  if (d >= NN) return;
  const int p0 = indptr[d], p1 = indptr[d+1];
  const float add = a2d[d];

  float mx = -3.4e38f;
  for (int e=p0+lane; e<p1; e+=64){
    int s = csr_src[e];
    mx = fmaxf(mx, lrelu(a2s[s] + add));
  }
#pragma unroll
  for (int off=32; off>=1; off>>=1) mx = fmaxf(mx, __shfl_xor(mx, off));

  float den = 0.f, num = 0.f;
  for (int e=p0+lane; e<p1; e+=64){
    int s = csr_src[e];
    float ev = lrelu(a2s[s] + add);
    float ex = __expf(ev - mx);
    den += ex;
    num = fmaf(ex, xh2[s], num);
  }
#pragma unroll
  for (int off=32; off>=1; off>>=1){ den += __shfl_xor(den, off); num += __shfl_xor(num, off); }
  if (lane == 0) out[d] = num/(den + 1e-16f) + b2[0];
}

// ---------------- launcher ----------------
extern "C" void kernel_launch(void* const* d_in, const int* in_sizes, int n_in,
                              void* d_out, int out_size, void* d_ws, size_t ws_size,
                              hipStream_t stream)
{
  const float* x    = (const float*)d_in[0];
  const int*   ei   = (const int*)d_in[1];
  const float* Wih0 = (const float*)d_in[2];
  const float* Whh0 = (const float*)d_in[3];
  const float* bih0 = (const float*)d_in[4];
  const float* bhh0 = (const float*)d_in[5];
  const float* Wih1 = (const float*)d_in[6];
  const float* Whh1 = (const float*)d_in[7];
  const float* bih1 = (const float*)d_in[8];
  const float* bhh1 = (const float*)d_in[9];
  const float* g1w  = (const float*)d_in[10];
  const float* g1as = (const float*)d_in[11];
  const float* g1ad = (const float*)d_in[12];
  const float* g1b  = (const float*)d_in[13];
  const float* g2w  = (const float*)d_in[14];
  const float* g2as = (const float*)d_in[15];
  const float* g2ad = (const float*)d_in[16];
  const float* g2b  = (const float*)d_in[17];

  float* ws  = (float*)d_ws;
  unsigned short* Wpk = (unsigned short*)ws;   // 114688 shorts = 57344 f32 slots
  float* b0  = ws + 57344;            // 256
  float* b1  = b0 + 256;              // 256
  float* h1  = b1 + 256;              // 20000*64
  float* xh  = h1 + 1280000;          // 20000*256
  float* als = xh + 5120000;          // 80000
  float* ald = als + 80000;           // 80000
  float* xh2 = ald + 80000;           // 20000
  float* a2s = xh2 + 20000;           // 20000
  float* a2d = a2s + 20000;           // 20000
  int*   deg    = (int*)(a2d + 20000);   // 20000
  int*   indptr = deg + 20000;           // 20001
  int*   cursor = indptr + 20001;        // 20000
  int*   csr    = cursor + 20000;        // 340000

  kzero_int<<<(NN+255)/256, 256, 0, stream>>>(deg, NN);
  pack_weights<<<450, 256, 0, stream>>>(Wih0,Whh0,bih0,bhh0,Wih1,Whh1,bih1,bhh1,Wpk,b0,b1);
  count_deg<<<(ETOT+255)/256, 256, 0, stream>>>(ei, deg);
  scan_deg<<<1, 256, 0, stream>>>(deg, indptr, cursor);
  scatter_edges<<<(ETOT+255)/256, 256, 0, stream>>>(ei, cursor, csr);
  lstm_mfma<<<250, 1024, 0, stream>>>(x, Wpk, b0, b1, h1);
  gat1_prep<<<NN/8, 256, 0, stream>>>(h1, g1w, g1as, g1ad, xh, als, ald);
  gat1_gather<<<(NN+3)/4, 256, 0, stream>>>(indptr, csr, als, ald, xh, g1b, g2w, g2as, g2ad, xh2, a2s, a2d);
  gat2_gather<<<(NN+3)/4, 256, 0, stream>>>(indptr, csr, a2s, a2d, xh2, g2b, (float*)d_out);
}

// Round 11
// 405.750 us; speedup vs baseline: 1.8265x; 1.0175x over previous
//
#include <hip/hip_runtime.h>
#include <math.h>

#define NN   20000
#define TT   32
#define INF_ 32
#define HID  64
#define NH   4
#define EE   320000
#define ETOT (EE + NN)
#define ZROW 164   // shorts/row: 160 data + 4 pad; node stride 41x8B-units (odd) -> b64 conflict-free
#define NB   80    // nodes per LSTM block; 250*80 = 20000 exact

typedef __attribute__((ext_vector_type(8))) short bf16x8;
typedef __attribute__((ext_vector_type(4))) short short4v;
typedef __attribute__((ext_vector_type(4))) float f32x4;

static __device__ __forceinline__ float lrelu(float x){ return x>0.0f ? x : 0.2f*x; }

static __device__ __forceinline__ unsigned short f2bf(float f){
  unsigned u = __float_as_uint(f);
  unsigned r = u + 0x7fffu + ((u>>16)&1u);
  return (unsigned short)(r>>16);
}
static __device__ __forceinline__ float bf2f(unsigned short h){ return __uint_as_float(((unsigned)h)<<16); }

// fused LSTM cell: 5 exp + 2 rcp
static __device__ __forceinline__ float lstm_cell(float gi, float gf, float gg, float go, float& c){
  float ef = __expf(-gf), ei = __expf(-gi), eg = __expf(-2.0f*gg);
  float pN = c*(1.0f+ei)*(1.0f+eg) + (1.0f-eg)*(1.0f+ef);
  float pD = (1.0f+ef)*(1.0f+ei)*(1.0f+eg);
  float cc = pN * __builtin_amdgcn_rcpf(pD);
  c = cc;
  float eo = __expf(-go), ec = __expf(-2.0f*cc);
  return (1.0f-ec) * __builtin_amdgcn_rcpf((1.0f+eo)*(1.0f+ec));
}

static __device__ __forceinline__ void edge_sd(const int* __restrict__ ei, int e, int& s, int& d){
  if (e < EE){ s = ei[e]; d = ei[EE + e]; } else { s = e - EE; d = s; }
}

// ---------------- utility kernels ----------------
__global__ void kzero_int(int* __restrict__ p, int n){
  int i = blockIdx.x*256 + threadIdx.x;
  if (i < n) p[i] = 0;
}

// Pack weights into MFMA A-frag layout, rows permuted so C/D row = 4*unitLocal + gateType.
// tile index tl = 0..15 (one per wave). g = (pr&3)*64 + tl*4 + (pr>>2). (verified R9)
__global__ void pack_weights(const float* __restrict__ Wih0, const float* __restrict__ Whh0,
                             const float* __restrict__ bih0, const float* __restrict__ bhh0,
                             const float* __restrict__ Wih1, const float* __restrict__ Whh1,
                             const float* __restrict__ bih1, const float* __restrict__ bhh1,
                             unsigned short* __restrict__ Wpk,
                             float* __restrict__ b0, float* __restrict__ b1){
  int idx = blockIdx.x*256 + threadIdx.x;
  if (idx < 49152){
    int fb = idx >> 9;            // (tl*3+ks)*2+h
    int h  = fb & 1;
    int t2 = fb >> 1;
    int ks = t2 % 3, tl = t2 / 3;
    int r  = idx & 511;
    int l  = r >> 3, j = r & 7;
    int pr = l & 15;
    int g  = (pr&3)*64 + tl*4 + (pr>>2);
    int k  = ks*32 + 4*(l>>4) + (j & 3) + 16*(j >> 2);
    float src = (k < 32) ? Wih0[g*32 + k] : Whh0[g*64 + (k - 32)];
    unsigned short hi = f2bf(src);
    Wpk[idx] = h ? f2bf(src - bf2f(hi)) : hi;
  } else if (idx < 114688){
    int idx2 = idx - 49152;
    int fb = idx2 >> 9;           // (tl*4+ks)*2+h
    int h  = fb & 1;
    int t2 = fb >> 1;
    int ks = t2 & 3, tl = t2 >> 2;
    int r  = idx2 & 511;
    int l  = r >> 3, j = r & 7;
    int pr = l & 15;
    int g  = (pr&3)*64 + tl*4 + (pr>>2);
    int k  = ks*32 + 4*(l>>4) + (j & 3) + 16*(j >> 2);
    float src = (k < 64) ? Wih1[g*64 + k] : Whh1[g*64 + (k - 64)];
    unsigned short hi = f2bf(src);
    Wpk[idx] = h ? f2bf(src - bf2f(hi)) : hi;
  } else {
    int m = idx - 114688;
    if (m < 256) b0[m] = bih0[m] + bhh0[m];
    else if (m < 512) b1[m-256] = bih1[m-256] + bhh1[m-256];
  }
}

// ---------------- CSR build (dst-indexed) ----------------
__global__ void count_deg(const int* __restrict__ ei, int* __restrict__ deg){
  int e = blockIdx.x*256 + threadIdx.x;
  if (e >= ETOT) return;
  int s, d; edge_sd(ei, e, s, d);
  atomicAdd(deg + d, 1);
}

__global__ void scan_deg(const int* __restrict__ deg, int* __restrict__ indptr, int* __restrict__ cursor){
  __shared__ int part[256];
  const int t = threadIdx.x;
  const int CH = (NN + 255) / 256;
  const int c0 = t * CH;
  int sum = 0;
  for (int i=0;i<CH;i++){ int idx=c0+i; if (idx<NN) sum += deg[idx]; }
  part[t] = sum; __syncthreads();
  int val = sum;
  for (int off=1; off<256; off<<=1){
    int add = (t>=off) ? part[t-off] : 0;
    __syncthreads();
    val += add; part[t] = val;
    __syncthreads();
  }
  int run = val - sum;
  for (int i=0;i<CH;i++){
    int idx=c0+i;
    if (idx<NN){ indptr[idx]=run; cursor[idx]=run; run += deg[idx]; }
  }
  if (t == 0) indptr[NN] = ETOT;
}

__global__ void scatter_edges(const int* __restrict__ ei, int* __restrict__ cursor, int* __restrict__ csr_src){
  int e = blockIdx.x*256 + threadIdx.x;
  if (e >= ETOT) return;
  int s, d; edge_sd(ei, e, s, d);
  int pos = atomicAdd(cursor + d, 1);
  csr_src[pos] = s;
}

// pin a 16B weight fragment into VGPRs: opaque to compiler -> cannot be rematerialized
#define PIN_LOAD(dst, p) asm volatile( \
    "global_load_dwordx4 %0, %1, off\n\t" \
    "s_waitcnt vmcnt(0)" \
    : "=&v"(dst) : "v"(p))

// ---------------- MFMA split-bf16 2-layer LSTM: 16 waves, 2 barriers/t ----------------
__global__ __launch_bounds__(1024)
__attribute__((amdgpu_waves_per_eu(4, 4)))
void lstm_mfma(
    const float* __restrict__ x,
    const unsigned short* __restrict__ Wpk,
    const float* __restrict__ b0, const float* __restrict__ b1,
    float* __restrict__ h1out)
{
  __shared__ unsigned short Zh[NB*ZROW];   // 26.2 KB
  __shared__ unsigned short Zl[NB*ZROW];   // 26.2 KB

  const int tid  = threadIdx.x;
  const int lane = tid & 63;
  const int w    = __builtin_amdgcn_readfirstlane(tid >> 6);   // 0..15
  const int ln15 = lane & 15;
  const int lq   = lane >> 4;                                  // 0..3
  const int gbase = blockIdx.x * NB;

  const bf16x8* wp = (const bf16x8*)Wpk;

  // ---- pin 14 weight fragments in registers (56 VGPRs) ----
  bf16x8 wA0h[3], wA0l[3], wA1h[4], wA1l[4];
#pragma unroll
  for (int ks=0; ks<3; ++ks){
    PIN_LOAD(wA0h[ks], wp + ((w*3+ks)*2+0)*64 + lane);
    PIN_LOAD(wA0l[ks], wp + ((w*3+ks)*2+1)*64 + lane);
  }
#pragma unroll
  for (int ks=0; ks<4; ++ks){
    PIN_LOAD(wA1h[ks], wp + 6144 + ((w*4+ks)*2+0)*64 + lane);
    PIN_LOAD(wA1l[ks], wp + 6144 + ((w*4+ks)*2+1)*64 + lane);
  }

  // bias per lane: bv[j] = b[j*64 + w*4 + lq]
  f32x4 bv0, bv1;
  {
    const int u = w*4 + lq;
#pragma unroll
    for (int j=0; j<4; ++j){ bv0[j] = b0[j*64+u]; bv1[j] = b1[j*64+u]; }
  }

  // x staging: threads 0..639, one quad each: node xn=tid>>3, k=(tid&7)*4
  const int xn = tid >> 3;
  const int xk = (tid & 7) * 4;
  const float* xp = x + (size_t)(gbase + ((xn < NB) ? xn : 0))*(TT*INF_) + xk;
  const bool xth = (tid < 640);

// packed bf16 hi/lo staging of a float4 into Zh/Zl (little-endian pairs)
#define XSTAGE(v) {                                                       \
    unsigned pkA, pkB, plA, plB;                                          \
    asm("v_cvt_pk_bf16_f32 %0,%1,%2":"=v"(pkA):"v"((v).x),"v"((v).y));    \
    asm("v_cvt_pk_bf16_f32 %0,%1,%2":"=v"(pkB):"v"((v).z),"v"((v).w));    \
    float l0_ = (v).x - __uint_as_float(pkA<<16);                         \
    float l1_ = (v).y - __uint_as_float(pkA & 0xffff0000u);               \
    float l2_ = (v).z - __uint_as_float(pkB<<16);                         \
    float l3_ = (v).w - __uint_as_float(pkB & 0xffff0000u);               \
    asm("v_cvt_pk_bf16_f32 %0,%1,%2":"=v"(plA):"v"(l0_),"v"(l1_));        \
    asm("v_cvt_pk_bf16_f32 %0,%1,%2":"=v"(plB):"v"(l2_),"v"(l3_));        \
    *(uint2*)&Zh[xn*ZROW + xk] = make_uint2(pkA, pkB);                    \
    *(uint2*)&Zl[xn*ZROW + xk] = make_uint2(plA, plB); }

  // ---- prologue: zero Z, stage x(0) ----
  for (int i = tid; i < NB*ZROW/2; i += 1024){ ((unsigned*)Zh)[i] = 0; ((unsigned*)Zl)[i] = 0; }
  __syncthreads();
  if (xth){
    float4 v = *(const float4*)xp;
    XSTAGE(v);
  }
  __syncthreads();

  float c0[5], c1[5];
#pragma unroll
  for (int i=0;i<5;i++){ c0[i]=0.f; c1[i]=0.f; }
  f32x4 aL1[5];

#define ZFRAG(Zb, node, kz) ({                                            \
    const unsigned short* _p = &Zb[(node)*ZROW + (kz) + 4*lq];            \
    short4v _a = *(const short4v*)_p;                                     \
    short4v _b = *(const short4v*)(_p + 16);                              \
    __builtin_shufflevector(_a, _b, 0,1,2,3,4,5,6,7); })

#define MF(acc, A, B) acc = __builtin_amdgcn_mfma_f32_16x16x32_bf16((A),(B),(acc),0,0,0)

// write a PAIR of h values (rows GA*16+ln15, GB*16+ln15) at column col, packed conversions
#define WPAIR(ha, hb, GA, GB, col) {                                      \
    unsigned pk_, pl_;                                                    \
    asm("v_cvt_pk_bf16_f32 %0,%1,%2":"=v"(pk_):"v"(ha),"v"(hb));          \
    float la_ = (ha) - __uint_as_float(pk_<<16);                          \
    float lb_ = (hb) - __uint_as_float(pk_ & 0xffff0000u);                \
    asm("v_cvt_pk_bf16_f32 %0,%1,%2":"=v"(pl_):"v"(la_),"v"(lb_));        \
    Zh[((GA)*16+ln15)*ZROW + (col)] = (unsigned short)pk_;                \
    Zh[((GB)*16+ln15)*ZROW + (col)] = (unsigned short)(pk_>>16);          \
    Zl[((GA)*16+ln15)*ZROW + (col)] = (unsigned short)pl_;                \
    Zl[((GB)*16+ln15)*ZROW + (col)] = (unsigned short)(pl_>>16); }

#define WSINGLE(hv, GG, col) {                                            \
    const int _n = (GG)*16 + ln15;                                        \
    const unsigned short _hh = f2bf(hv);                                  \
    Zh[_n*ZROW + (col)] = _hh;                                            \
    Zl[_n*ZROW + (col)] = f2bf((hv) - bf2f(_hh)); }

#define CHUNK(ACCS, KZ, WH, WL)                                           \
    _Pragma("unroll")                                                     \
    for (int GG=0; GG<5; ++GG){                                           \
      const bf16x8 zh = ZFRAG(Zh, GG*16+ln15, KZ);                        \
      const bf16x8 zl = ZFRAG(Zl, GG*16+ln15, KZ);                        \
      MF(ACCS[GG], WH, zh); MF(ACCS[GG], WH, zl); MF(ACCS[GG], WL, zh);   \
    }

  for (int t=0; t<TT; ++t){
    // ====== P1: x(t+1) load issue; L0 ks0 MFMA; L1-cells(t-1)->H1; L0 ks1,ks2 ======
    float4 xv;
    const bool dox = xth && (t+1 < TT);
    if (dox) xv = *(const float4*)(xp + (size_t)(t+1)*INF_);

    f32x4 aL0[5];
#pragma unroll
    for (int GG=0; GG<5; ++GG) aL0[GG] = bv0;

    CHUNK(aL0, 0, wA0h[0], wA0l[0]);          // ks=0 (x slab)

    if (t > 0){
      const int uc = 96 + w*4 + lq;
      float h0_ = lstm_cell(aL1[0][0], aL1[0][1], aL1[0][2], aL1[0][3], c1[0]);
      float h1_ = lstm_cell(aL1[1][0], aL1[1][1], aL1[1][2], aL1[1][3], c1[1]);
      float h2_ = lstm_cell(aL1[2][0], aL1[2][1], aL1[2][2], aL1[2][3], c1[2]);
      float h3_ = lstm_cell(aL1[3][0], aL1[3][1], aL1[3][2], aL1[3][3], c1[3]);
      float h4_ = lstm_cell(aL1[4][0], aL1[4][1], aL1[4][2], aL1[4][3], c1[4]);
      WPAIR(h0_, h1_, 0, 1, uc); WPAIR(h2_, h3_, 2, 3, uc); WSINGLE(h4_, 4, uc);
    }

    CHUNK(aL0, 32, wA0h[1], wA0l[1]);         // ks=1 (h0 slab a)
    CHUNK(aL0, 64, wA0h[2], wA0l[2]);         // ks=2 (h0 slab b)
    __syncthreads();

    // ====== P2: L1 ks2 (H1); L0-cells->H0 + x(t+1) write; L1 ks3 (H1) ======
#pragma unroll
    for (int GG=0; GG<5; ++GG) aL1[GG] = bv1;

    CHUNK(aL1, 96, wA1h[2], wA1l[2]);         // L1 ks=2 (h1 slab a)

    {
      const int uc = 32 + w*4 + lq;
      float h0_ = lstm_cell(aL0[0][0], aL0[0][1], aL0[0][2], aL0[0][3], c0[0]);
      float h1_ = lstm_cell(aL0[1][0], aL0[1][1], aL0[1][2], aL0[1][3], c0[1]);
      float h2_ = lstm_cell(aL0[2][0], aL0[2][1], aL0[2][2], aL0[2][3], c0[2]);
      float h3_ = lstm_cell(aL0[3][0], aL0[3][1], aL0[3][2], aL0[3][3], c0[3]);
      float h4_ = lstm_cell(aL0[4][0], aL0[4][1], aL0[4][2], aL0[4][3], c0[4]);
      WPAIR(h0_, h1_, 0, 1, uc); WPAIR(h2_, h3_, 2, 3, uc); WSINGLE(h4_, 4, uc);
    }
    if (dox) XSTAGE(xv);

    CHUNK(aL1, 128, wA1h[3], wA1l[3]);        // L1 ks=3 (h1 slab b)
    __syncthreads();

    // ====== P3: L1 ks0,ks1 (H0 just written) — NO trailing barrier ======
    CHUNK(aL1, 32, wA1h[0], wA1l[0]);
    CHUNK(aL1, 64, wA1h[1], wA1l[1]);
    // safe: next P1 writes H1 (96..159) / reads x,H0 — disjoint from P3 reads (32..95)
  }

  // final L1 cells -> H1
  {
    const int uc = 96 + w*4 + lq;
    float h0_ = lstm_cell(aL1[0][0], aL1[0][1], aL1[0][2], aL1[0][3], c1[0]);
    float h1_ = lstm_cell(aL1[1][0], aL1[1][1], aL1[1][2], aL1[1][3], c1[1]);
    float h2_ = lstm_cell(aL1[2][0], aL1[2][1], aL1[2][2], aL1[2][3], c1[2]);
    float h3_ = lstm_cell(aL1[3][0], aL1[3][1], aL1[3][2], aL1[3][3], c1[3]);
    float h4_ = lstm_cell(aL1[4][0], aL1[4][1], aL1[4][2], aL1[4][3], c1[4]);
    WPAIR(h0_, h1_, 0, 1, uc); WPAIR(h2_, h3_, 2, 3, uc); WSINGLE(h4_, 4, uc);
  }
  __syncthreads();

  // epilogue: coalesced h1 write
  for (int o = tid; o < NB*64; o += 1024){
    const int n = o >> 6, u = o & 63;
    h1out[(size_t)(gbase+n)*64 + u] = bf2f(Zh[n*ZROW + 96 + u]) + bf2f(Zl[n*ZROW + 96 + u]);
  }
#undef ZFRAG
#undef MF
#undef WPAIR
#undef WSINGLE
#undef CHUNK
#undef XSTAGE
}

// ---------------- GAT layer 1 prep: 16 nodes/block (amortize W reads) ----------------
__global__ __launch_bounds__(256) void gat1_prep(const float* __restrict__ h1, const float* __restrict__ W,
  const float* __restrict__ as_, const float* __restrict__ ad_,
  float* __restrict__ xh, float* __restrict__ als, float* __restrict__ ald)
{
  __shared__ float hs[16][64];
  const int nb0 = blockIdx.x * 16;
  const int o  = threadIdx.x;
  const int q  = o >> 6, u = o & 63;
  for (int i = o; i < 1024; i += 256){
    hs[i>>6][i&63] = h1[(size_t)(nb0 + (i>>6))*64 + (i&63)];
  }
  __syncthreads();
  float acc[16];
#pragma unroll
  for (int nd=0; nd<16; ++nd) acc[nd] = 0.f;
  for (int k=0; k<64; ++k){
    const float wv = W[k*256 + o];
#pragma unroll
    for (int nd=0; nd<16; ++nd) acc[nd] = fmaf(hs[nd][k], wv, acc[nd]);
  }
  const float asv = as_[o], adv = ad_[o];
#pragma unroll
  for (int nd=0; nd<16; ++nd){
    xh[(size_t)(nb0+nd)*256 + o] = acc[nd];
    float ps = acc[nd] * asv;
    float pd = acc[nd] * adv;
#pragma unroll
    for (int off=32; off>=1; off>>=1){ ps += __shfl_xor(ps, off); pd += __shfl_xor(pd, off); }
    if (u == 0){ als[(nb0+nd)*4 + q] = ps; ald[(nb0+nd)*4 + q] = pd; }
  }
}

// ---------------- GAT1 gather + fused epilogue ----------------
__global__ __launch_bounds__(256) void gat1_gather(
  const int* __restrict__ indptr, const int* __restrict__ csr_src,
  const float* __restrict__ als, const float* __restrict__ ald,
  const float* __restrict__ xh,  const float* __restrict__ b1g,
  const float* __restrict__ w2,  const float* __restrict__ as2, const float* __restrict__ ad2,
  float* __restrict__ xh2, float* __restrict__ a2s, float* __restrict__ a2d)
{
  const int d = blockIdx.x*4 + (threadIdx.x >> 6);
  const int lane = threadIdx.x & 63;
  if (d >= NN) return;
  const int p0 = indptr[d], p1 = indptr[d+1];

  float aldv[4];
#pragma unroll
  for (int q=0;q<4;q++) aldv[q] = ald[d*4+q];

  float mx[4];
#pragma unroll
  for (int q=0;q<4;q++) mx[q] = -3.4e38f;
  for (int e=p0+lane; e<p1; e+=64){
    int s = csr_src[e];
#pragma unroll
    for (int q=0;q<4;q++){
      float ev = lrelu(als[s*4+q] + aldv[q]);
      mx[q] = fmaxf(mx[q], ev);
    }
  }
#pragma unroll
  for (int off=32; off>=1; off>>=1){
#pragma unroll
    for (int q=0;q<4;q++) mx[q] = fmaxf(mx[q], __shfl_xor(mx[q], off));
  }

  const int q = lane >> 4;
  const float mq = mx[q];
  const float aldq = aldv[q];
  float ax=0.f, ay=0.f, az=0.f, aw=0.f, den=0.f;
  int s_next = (p0 < p1) ? csr_src[p0] : 0;
  for (int e=p0; e<p1; ++e){
    const int s = s_next;
    if (e+1 < p1) s_next = csr_src[e+1];
    float ev = lrelu(als[s*4+q] + aldq);
    float ex = __expf(ev - mq);
    den += ex;
    float4 v = *(const float4*)(xh + (size_t)s*256 + lane*4);
    ax = fmaf(ex, v.x, ax); ay = fmaf(ex, v.y, ay);
    az = fmaf(ex, v.z, az); aw = fmaf(ex, v.w, aw);
  }
  const float rr = 1.0f/(den + 1e-16f);
  const int o = lane*4;
  float v0 = ax*rr + b1g[o+0];
  float v1 = ay*rr + b1g[o+1];
  float v2 = az*rr + b1g[o+2];
  float v3 = aw*rr + b1g[o+3];
  v0 = v0>0.f?v0:0.f; v1 = v1>0.f?v1:0.f; v2 = v2>0.f?v2:0.f; v3 = v3>0.f?v3:0.f;
  float part = v0*w2[o+0] + v1*w2[o+1] + v2*w2[o+2] + v3*w2[o+3];
#pragma unroll
  for (int off=32; off>=1; off>>=1) part += __shfl_xor(part, off);
  if (lane == 0){
    xh2[d] = part;
    a2s[d] = part * as2[0];
    a2d[d] = part * ad2[0];
  }
}

// ---------------- GAT2 gather ----------------
__global__ __launch_bounds__(256) void gat2_gather(
  const int* __restrict__ indptr, const int* __restrict__ csr_src,
  const float* __restrict__ a2s, const float* __restrict__ a2d,
  const float* __restrict__ xh2, const float* __restrict__ b2,
  float* __restrict__ out)
{
  const int d = blockIdx.x*4 + (threadIdx.x >> 6);
  const int lane = threadIdx.x & 63;
  if (d >= NN) return;
  const int p0 = indptr[d], p1 = indptr[d+1];
  const float add = a2d[d];

  float mx = -3.4e38f;
  for (int e=p0+lane; e<p1; e+=64){
    int s = csr_src[e];
    mx = fmaxf(mx, lrelu(a2s[s] + add));
  }
#pragma unroll
  for (int off=32; off>=1; off>>=1) mx = fmaxf(mx, __shfl_xor(mx, off));

  float den = 0.f, num = 0.f;
  for (int e=p0+lane; e<p1; e+=64){
    int s = csr_src[e];
    float ev = lrelu(a2s[s] + add);
    float ex = __expf(ev - mx);
    den += ex;
    num = fmaf(ex, xh2[s], num);
  }
#pragma unroll
  for (int off=32; off>=1; off>>=1){ den += __shfl_xor(den, off); num += __shfl_xor(num, off); }
  if (lane == 0) out[d] = num/(den + 1e-16f) + b2[0];
}

// ---------------- launcher ----------------
extern "C" void kernel_launch(void* const* d_in, const int* in_sizes, int n_in,
                              void* d_out, int out_size, void* d_ws, size_t ws_size,
                              hipStream_t stream)
{
  const float* x    = (const float*)d_in[0];
  const int*   ei   = (const int*)d_in[1];
  const float* Wih0 = (const float*)d_in[2];
  const float* Whh0 = (const float*)d_in[3];
  const float* bih0 = (const float*)d_in[4];
  const float* bhh0 = (const float*)d_in[5];
  const float* Wih1 = (const float*)d_in[6];
  const float* Whh1 = (const float*)d_in[7];
  const float* bih1 = (const float*)d_in[8];
  const float* bhh1 = (const float*)d_in[9];
  const float* g1w  = (const float*)d_in[10];
  const float* g1as = (const float*)d_in[11];
  const float* g1ad = (const float*)d_in[12];
  const float* g1b  = (const float*)d_in[13];
  const float* g2w  = (const float*)d_in[14];
  const float* g2as = (const float*)d_in[15];
  const float* g2ad = (const float*)d_in[16];
  const float* g2b  = (const float*)d_in[17];

  float* ws  = (float*)d_ws;
  unsigned short* Wpk = (unsigned short*)ws;   // 114688 shorts = 57344 f32 slots
  float* b0  = ws + 57344;            // 256
  float* b1  = b0 + 256;              // 256
  float* h1  = b1 + 256;              // 20000*64
  float* xh  = h1 + 1280000;          // 20000*256
  float* als = xh + 5120000;          // 80000
  float* ald = als + 80000;           // 80000
  float* xh2 = ald + 80000;           // 20000
  float* a2s = xh2 + 20000;           // 20000
  float* a2d = a2s + 20000;           // 20000
  int*   deg    = (int*)(a2d + 20000);   // 20000
  int*   indptr = deg + 20000;           // 20001
  int*   cursor = indptr + 20001;        // 20000
  int*   csr    = cursor + 20000;        // 340000

  kzero_int<<<(NN+255)/256, 256, 0, stream>>>(deg, NN);
  pack_weights<<<450, 256, 0, stream>>>(Wih0,Whh0,bih0,bhh0,Wih1,Whh1,bih1,bhh1,Wpk,b0,b1);
  count_deg<<<(ETOT+255)/256, 256, 0, stream>>>(ei, deg);
  scan_deg<<<1, 256, 0, stream>>>(deg, indptr, cursor);
  scatter_edges<<<(ETOT+255)/256, 256, 0, stream>>>(ei, cursor, csr);
  lstm_mfma<<<250, 1024, 0, stream>>>(x, Wpk, b0, b1, h1);
  gat1_prep<<<NN/16, 256, 0, stream>>>(h1, g1w, g1as, g1ad, xh, als, ald);
  gat1_gather<<<(NN+3)/4, 256, 0, stream>>>(indptr, csr, als, ald, xh, g1b, g2w, g2as, g2ad, xh2, a2s, a2d);
  gat2_gather<<<(NN+3)/4, 256, 0, stream>>>(indptr, csr, a2s, a2d, xh2, g2b, (float*)d_out);
}

// Round 12
// 405.238 us; speedup vs baseline: 1.8288x; 1.0013x over previous
//
#include <hip/hip_runtime.h>
#include <math.h>

#define NN   20000
#define TT   32
#define INF_ 32
#define HID  64
#define NH   4
#define EE   320000
#define ETOT (EE + NN)
#define ZROW 168   // shorts/row = 5 chunks x 32 + 8 pad; 336B rows: b128 frag reads hit 8-phase minimum
#define NB   80    // nodes per LSTM block; 250*80 = 20000 exact

typedef __attribute__((ext_vector_type(8))) short bf16x8;
typedef __attribute__((ext_vector_type(4))) float f32x4;

static __device__ __forceinline__ float lrelu(float x){ return x>0.0f ? x : 0.2f*x; }

static __device__ __forceinline__ unsigned short f2bf(float f){
  unsigned u = __float_as_uint(f);
  unsigned r = u + 0x7fffu + ((u>>16)&1u);
  return (unsigned short)(r>>16);
}
static __device__ __forceinline__ float bf2f(unsigned short h){ return __uint_as_float(((unsigned)h)<<16); }

// chunk-local permuted position for k' (0..31): frag elem j of lane (ln15,lq) sits at p = lq*8+j
static __device__ __forceinline__ int zpos(int kq){
  return (kq&3) + (((kq>>4)&1)<<2) + (((kq>>2)&3)<<3);
}

// fused LSTM cell: 5 exp + 2 rcp
static __device__ __forceinline__ float lstm_cell(float gi, float gf, float gg, float go, float& c){
  float ef = __expf(-gf), ei = __expf(-gi), eg = __expf(-2.0f*gg);
  float pN = c*(1.0f+ei)*(1.0f+eg) + (1.0f-eg)*(1.0f+ef);
  float pD = (1.0f+ef)*(1.0f+ei)*(1.0f+eg);
  float cc = pN * __builtin_amdgcn_rcpf(pD);
  c = cc;
  float eo = __expf(-go), ec = __expf(-2.0f*cc);
  return (1.0f-ec) * __builtin_amdgcn_rcpf((1.0f+eo)*(1.0f+ec));
}

static __device__ __forceinline__ void edge_sd(const int* __restrict__ ei, int e, int& s, int& d){
  if (e < EE){ s = ei[e]; d = ei[EE + e]; } else { s = e - EE; d = s; }
}

// ---------------- utility kernels ----------------
__global__ void kzero_int(int* __restrict__ p, int n){
  int i = blockIdx.x*256 + threadIdx.x;
  if (i < n) p[i] = 0;
}

// Pack weights into MFMA A-frag layout, rows permuted so C/D row = 4*unitLocal + gateType.
// tile index tl = 0..15 (one per wave). g = (pr&3)*64 + tl*4 + (pr>>2). (verified R9/R10)
__global__ void pack_weights(const float* __restrict__ Wih0, const float* __restrict__ Whh0,
                             const float* __restrict__ bih0, const float* __restrict__ bhh0,
                             const float* __restrict__ Wih1, const float* __restrict__ Whh1,
                             const float* __restrict__ bih1, const float* __restrict__ bhh1,
                             unsigned short* __restrict__ Wpk,
                             float* __restrict__ b0, float* __restrict__ b1){
  int idx = blockIdx.x*256 + threadIdx.x;
  if (idx < 49152){
    int fb = idx >> 9;            // (tl*3+ks)*2+h
    int h  = fb & 1;
    int t2 = fb >> 1;
    int ks = t2 % 3, tl = t2 / 3;
    int r  = idx & 511;
    int l  = r >> 3, j = r & 7;
    int pr = l & 15;
    int g  = (pr&3)*64 + tl*4 + (pr>>2);
    int k  = ks*32 + 4*(l>>4) + (j & 3) + 16*(j >> 2);
    float src = (k < 32) ? Wih0[g*32 + k] : Whh0[g*64 + (k - 32)];
    unsigned short hi = f2bf(src);
    Wpk[idx] = h ? f2bf(src - bf2f(hi)) : hi;
  } else if (idx < 114688){
    int idx2 = idx - 49152;
    int fb = idx2 >> 9;           // (tl*4+ks)*2+h
    int h  = fb & 1;
    int t2 = fb >> 1;
    int ks = t2 & 3, tl = t2 >> 2;
    int r  = idx2 & 511;
    int l  = r >> 3, j = r & 7;
    int pr = l & 15;
    int g  = (pr&3)*64 + tl*4 + (pr>>2);
    int k  = ks*32 + 4*(l>>4) + (j & 3) + 16*(j >> 2);
    float src = (k < 64) ? Wih1[g*64 + k] : Whh1[g*64 + (k - 64)];
    unsigned short hi = f2bf(src);
    Wpk[idx] = h ? f2bf(src - bf2f(hi)) : hi;
  } else {
    int m = idx - 114688;
    if (m < 256) b0[m] = bih0[m] + bhh0[m];
    else if (m < 512) b1[m-256] = bih1[m-256] + bhh1[m-256];
  }
}

// ---------------- CSR build (dst-indexed) ----------------
__global__ void count_deg(const int* __restrict__ ei, int* __restrict__ deg){
  int e = blockIdx.x*256 + threadIdx.x;
  if (e >= ETOT) return;
  int s, d; edge_sd(ei, e, s, d);
  atomicAdd(deg + d, 1);
}

__global__ void scan_deg(const int* __restrict__ deg, int* __restrict__ indptr, int* __restrict__ cursor){
  __shared__ int part[256];
  const int t = threadIdx.x;
  const int CH = (NN + 255) / 256;
  const int c0 = t * CH;
  int sum = 0;
  for (int i=0;i<CH;i++){ int idx=c0+i; if (idx<NN) sum += deg[idx]; }
  part[t] = sum; __syncthreads();
  int val = sum;
  for (int off=1; off<256; off<<=1){
    int add = (t>=off) ? part[t-off] : 0;
    __syncthreads();
    val += add; part[t] = val;
    __syncthreads();
  }
  int run = val - sum;
  for (int i=0;i<CH;i++){
    int idx=c0+i;
    if (idx<NN){ indptr[idx]=run; cursor[idx]=run; run += deg[idx]; }
  }
  if (t == 0) indptr[NN] = ETOT;
}

__global__ void scatter_edges(const int* __restrict__ ei, int* __restrict__ cursor, int* __restrict__ csr_src){
  int e = blockIdx.x*256 + threadIdx.x;
  if (e >= ETOT) return;
  int s, d; edge_sd(ei, e, s, d);
  int pos = atomicAdd(cursor + d, 1);
  csr_src[pos] = s;
}

// pin a 16B weight fragment into VGPRs: opaque to compiler -> cannot be rematerialized
#define PIN_LOAD(dst, p) asm volatile( \
    "global_load_dwordx4 %0, %1, off\n\t" \
    "s_waitcnt vmcnt(0)" \
    : "=&v"(dst) : "v"(p))

// ---------------- MFMA split-bf16 2-layer LSTM: 16 waves, b128 fragments ----------------
// Z chunks: [0]=x k0..31, [1]=h0 u0..31, [2]=h0 u32..63, [3]=h1 u0..31, [4]=h1 u32..63.
// Within chunk, permuted (zpos) so each MFMA B-fragment is one contiguous 16B ds_read_b128.
__global__ __launch_bounds__(1024)
__attribute__((amdgpu_waves_per_eu(4, 4)))
void lstm_mfma(
    const float* __restrict__ x,
    const unsigned short* __restrict__ Wpk,
    const float* __restrict__ b0, const float* __restrict__ b1,
    float* __restrict__ h1out)
{
  __shared__ unsigned short Zh[NB*ZROW];   // 26.9 KB
  __shared__ unsigned short Zl[NB*ZROW];   // 26.9 KB

  const int tid  = threadIdx.x;
  const int lane = tid & 63;
  const int w    = __builtin_amdgcn_readfirstlane(tid >> 6);   // 0..15
  const int ln15 = lane & 15;
  const int lq   = lane >> 4;                                  // 0..3
  const int gbase = blockIdx.x * NB;

  const bf16x8* wp = (const bf16x8*)Wpk;

  // ---- pin 14 weight fragments in registers (56 VGPRs) ----
  bf16x8 wA0h[3], wA0l[3], wA1h[4], wA1l[4];
#pragma unroll
  for (int ks=0; ks<3; ++ks){
    PIN_LOAD(wA0h[ks], wp + ((w*3+ks)*2+0)*64 + lane);
    PIN_LOAD(wA0l[ks], wp + ((w*3+ks)*2+1)*64 + lane);
  }
#pragma unroll
  for (int ks=0; ks<4; ++ks){
    PIN_LOAD(wA1h[ks], wp + 6144 + ((w*4+ks)*2+0)*64 + lane);
    PIN_LOAD(wA1l[ks], wp + 6144 + ((w*4+ks)*2+1)*64 + lane);
  }

  // bias per lane: bv[j] = b[j*64 + w*4 + lq]
  f32x4 bv0, bv1;
  {
    const int u = w*4 + lq;
#pragma unroll
    for (int j=0; j<4; ++j){ bv0[j] = b0[j*64+u]; bv1[j] = b1[j*64+u]; }
  }

  // pointwise H-write columns (short index in Z row) for this thread's unit u = w*4+lq:
  // slot within chunk = zpos(u&31) = lq + 4*((w>>2)&1) + 8*(w&3); chunk = base + (w>>3)
  const int hs_ = lq + ((w & 4) ? 4 : 0) + 8*(w & 3);
  const int uc0 = (1 + (w>>3))*32 + hs_;   // h0 column
  const int uc1 = (3 + (w>>3))*32 + hs_;   // h1 column

  // x staging: threads 0..639, one quad each: node xn=tid>>3, k=(tid&7)*4 -> permuted slot (chunk 0)
  const int xn = tid >> 3;
  const int xk = (tid & 7) * 4;
  const int xslot = (((xk>>2)&3)<<3) + (((xk>>4)&1)<<2);
  const float* xp = x + (size_t)(gbase + ((xn < NB) ? xn : 0))*(TT*INF_) + xk;
  const bool xth = (tid < 640);

// packed bf16 hi/lo staging of a float4 into Zh/Zl chunk 0 (4 contiguous permuted slots)
#define XSTAGE(v) {                                                       \
    unsigned pkA, pkB, plA, plB;                                          \
    asm("v_cvt_pk_bf16_f32 %0,%1,%2":"=v"(pkA):"v"((v).x),"v"((v).y));    \
    asm("v_cvt_pk_bf16_f32 %0,%1,%2":"=v"(pkB):"v"((v).z),"v"((v).w));    \
    float l0_ = (v).x - __uint_as_float(pkA<<16);                         \
    float l1_ = (v).y - __uint_as_float(pkA & 0xffff0000u);               \
    float l2_ = (v).z - __uint_as_float(pkB<<16);                         \
    float l3_ = (v).w - __uint_as_float(pkB & 0xffff0000u);               \
    asm("v_cvt_pk_bf16_f32 %0,%1,%2":"=v"(plA):"v"(l0_),"v"(l1_));        \
    asm("v_cvt_pk_bf16_f32 %0,%1,%2":"=v"(plB):"v"(l2_),"v"(l3_));        \
    *(uint2*)&Zh[xn*ZROW + xslot] = make_uint2(pkA, pkB);                 \
    *(uint2*)&Zl[xn*ZROW + xslot] = make_uint2(plA, plB); }

  // ---- prologue: zero Z, stage x(0) ----
  for (int i = tid; i < NB*ZROW/2; i += 1024){ ((unsigned*)Zh)[i] = 0; ((unsigned*)Zl)[i] = 0; }
  __syncthreads();
  if (xth){
    float4 v = *(const float4*)xp;
    XSTAGE(v);
  }
  __syncthreads();

  float c0[5], c1[5];
#pragma unroll
  for (int i=0;i<5;i++){ c0[i]=0.f; c1[i]=0.f; }
  f32x4 aL1[5];

// single contiguous 16B fragment read (conflict-minimal: 336B row stride = 80 mod 128)
#define ZFRAG(Zb, node, ck) (*(const bf16x8*)&Zb[(node)*ZROW + (ck)*32 + lq*8])

#define MF(acc, A, B) acc = __builtin_amdgcn_mfma_f32_16x16x32_bf16((A),(B),(acc),0,0,0)

// write a PAIR of h values (rows GA*16+ln15, GB*16+ln15) at column col, packed conversions
#define WPAIR(ha, hb, GA, GB, col) {                                      \
    unsigned pk_, pl_;                                                    \
    asm("v_cvt_pk_bf16_f32 %0,%1,%2":"=v"(pk_):"v"(ha),"v"(hb));          \
    float la_ = (ha) - __uint_as_float(pk_<<16);                          \
    float lb_ = (hb) - __uint_as_float(pk_ & 0xffff0000u);                \
    asm("v_cvt_pk_bf16_f32 %0,%1,%2":"=v"(pl_):"v"(la_),"v"(lb_));        \
    Zh[((GA)*16+ln15)*ZROW + (col)] = (unsigned short)pk_;                \
    Zh[((GB)*16+ln15)*ZROW + (col)] = (unsigned short)(pk_>>16);          \
    Zl[((GA)*16+ln15)*ZROW + (col)] = (unsigned short)pl_;                \
    Zl[((GB)*16+ln15)*ZROW + (col)] = (unsigned short)(pl_>>16); }

#define WSINGLE(hv, GG, col) {                                            \
    const int _n = (GG)*16 + ln15;                                        \
    const unsigned short _hh = f2bf(hv);                                  \
    Zh[_n*ZROW + (col)] = _hh;                                            \
    Zl[_n*ZROW + (col)] = f2bf((hv) - bf2f(_hh)); }

#define CHUNK(ACCS, CK, WH, WL)                                           \
    _Pragma("unroll")                                                     \
    for (int GG=0; GG<5; ++GG){                                           \
      const bf16x8 zh = ZFRAG(Zh, GG*16+ln15, CK);                        \
      const bf16x8 zl = ZFRAG(Zl, GG*16+ln15, CK);                        \
      MF(ACCS[GG], WH, zh); MF(ACCS[GG], WH, zl); MF(ACCS[GG], WL, zh);   \
    }

  for (int t=0; t<TT; ++t){
    // ====== P1: x(t+1) load issue; L0 chunk0; L1-cells(t-1)->H1; L0 chunks 1,2 ======
    float4 xv;
    const bool dox = xth && (t+1 < TT);
    if (dox) xv = *(const float4*)(xp + (size_t)(t+1)*INF_);

    f32x4 aL0[5];
#pragma unroll
    for (int GG=0; GG<5; ++GG) aL0[GG] = bv0;

    CHUNK(aL0, 0, wA0h[0], wA0l[0]);          // x slab

    if (t > 0){
      float h0_ = lstm_cell(aL1[0][0], aL1[0][1], aL1[0][2], aL1[0][3], c1[0]);
      float h1_ = lstm_cell(aL1[1][0], aL1[1][1], aL1[1][2], aL1[1][3], c1[1]);
      float h2_ = lstm_cell(aL1[2][0], aL1[2][1], aL1[2][2], aL1[2][3], c1[2]);
      float h3_ = lstm_cell(aL1[3][0], aL1[3][1], aL1[3][2], aL1[3][3], c1[3]);
      float h4_ = lstm_cell(aL1[4][0], aL1[4][1], aL1[4][2], aL1[4][3], c1[4]);
      WPAIR(h0_, h1_, 0, 1, uc1); WPAIR(h2_, h3_, 2, 3, uc1); WSINGLE(h4_, 4, uc1);
    }

    CHUNK(aL0, 1, wA0h[1], wA0l[1]);          // h0 slab a
    CHUNK(aL0, 2, wA0h[2], wA0l[2]);          // h0 slab b
    __syncthreads();

    // ====== P2: L1 chunks 3,4 (H1(t-1)); L0-cells->H0 + x(t+1) write ======
#pragma unroll
    for (int GG=0; GG<5; ++GG) aL1[GG] = bv1;

    CHUNK(aL1, 3, wA1h[2], wA1l[2]);          // h1 slab a

    {
      float h0_ = lstm_cell(aL0[0][0], aL0[0][1], aL0[0][2], aL0[0][3], c0[0]);
      float h1_ = lstm_cell(aL0[1][0], aL0[1][1], aL0[1][2], aL0[1][3], c0[1]);
      float h2_ = lstm_cell(aL0[2][0], aL0[2][1], aL0[2][2], aL0[2][3], c0[2]);
      float h3_ = lstm_cell(aL0[3][0], aL0[3][1], aL0[3][2], aL0[3][3], c0[3]);
      float h4_ = lstm_cell(aL0[4][0], aL0[4][1], aL0[4][2], aL0[4][3], c0[4]);
      WPAIR(h0_, h1_, 0, 1, uc0); WPAIR(h2_, h3_, 2, 3, uc0); WSINGLE(h4_, 4, uc0);
    }
    if (dox) XSTAGE(xv);

    CHUNK(aL1, 4, wA1h[3], wA1l[3]);          // h1 slab b
    __syncthreads();

    // ====== P3: L1 chunks 1,2 (H0 just written) — no trailing barrier ======
    CHUNK(aL1, 1, wA1h[0], wA1l[0]);
    CHUNK(aL1, 2, wA1h[1], wA1l[1]);
    // safe: next P1 writes H1 (chunks 3,4) / reads x(chunk0),H0 — disjoint from P3 reads
  }

  // final L1 cells -> H1
  {
    float h0_ = lstm_cell(aL1[0][0], aL1[0][1], aL1[0][2], aL1[0][3], c1[0]);
    float h1_ = lstm_cell(aL1[1][0], aL1[1][1], aL1[1][2], aL1[1][3], c1[1]);
    float h2_ = lstm_cell(aL1[2][0], aL1[2][1], aL1[2][2], aL1[2][3], c1[2]);
    float h3_ = lstm_cell(aL1[3][0], aL1[3][1], aL1[3][2], aL1[3][3], c1[3]);
    float h4_ = lstm_cell(aL1[4][0], aL1[4][1], aL1[4][2], aL1[4][3], c1[4]);
    WPAIR(h0_, h1_, 0, 1, uc1); WPAIR(h2_, h3_, 2, 3, uc1); WSINGLE(h4_, 4, uc1);
  }
  __syncthreads();

  // epilogue: coalesced h1 write (permuted read: h1 unit u -> chunk 3+(u>>5), slot zpos(u&31))
  for (int o = tid; o < NB*64; o += 1024){
    const int n = o >> 6, u = o & 63;
    const int zp = (3 + (u>>5))*32 + zpos(u & 31);
    h1out[(size_t)(gbase+n)*64 + u] = bf2f(Zh[n*ZROW + zp]) + bf2f(Zl[n*ZROW + zp]);
  }
#undef ZFRAG
#undef MF
#undef WPAIR
#undef WSINGLE
#undef CHUNK
#undef XSTAGE
}

// ---------------- GAT layer 1 prep: 16 nodes/block (amortize W reads) ----------------
__global__ __launch_bounds__(256) void gat1_prep(const float* __restrict__ h1, const float* __restrict__ W,
  const float* __restrict__ as_, const float* __restrict__ ad_,
  float* __restrict__ xh, float* __restrict__ als, float* __restrict__ ald)
{
  __shared__ float hs[16][64];
  const int nb0 = blockIdx.x * 16;
  const int o  = threadIdx.x;
  const int q  = o >> 6, u = o & 63;
  for (int i = o; i < 1024; i += 256){
    hs[i>>6][i&63] = h1[(size_t)(nb0 + (i>>6))*64 + (i&63)];
  }
  __syncthreads();
  float acc[16];
#pragma unroll
  for (int nd=0; nd<16; ++nd) acc[nd] = 0.f;
  for (int k=0; k<64; ++k){
    const float wv = W[k*256 + o];
#pragma unroll
    for (int nd=0; nd<16; ++nd) acc[nd] = fmaf(hs[nd][k], wv, acc[nd]);
  }
  const float asv = as_[o], adv = ad_[o];
#pragma unroll
  for (int nd=0; nd<16; ++nd){
    xh[(size_t)(nb0+nd)*256 + o] = acc[nd];
    float ps = acc[nd] * asv;
    float pd = acc[nd] * adv;
#pragma unroll
    for (int off=32; off>=1; off>>=1){ ps += __shfl_xor(ps, off); pd += __shfl_xor(pd, off); }
    if (u == 0){ als[(nb0+nd)*4 + q] = ps; ald[(nb0+nd)*4 + q] = pd; }
  }
}

// ---------------- GAT1 gather + fused epilogue ----------------
__global__ __launch_bounds__(256) void gat1_gather(
  const int* __restrict__ indptr, const int* __restrict__ csr_src,
  const float* __restrict__ als, const float* __restrict__ ald,
  const float* __restrict__ xh,  const float* __restrict__ b1g,
  const float* __restrict__ w2,  const float* __restrict__ as2, const float* __restrict__ ad2,
  float* __restrict__ xh2, float* __restrict__ a2s, float* __restrict__ a2d)
{
  const int d = blockIdx.x*4 + (threadIdx.x >> 6);
  const int lane = threadIdx.x & 63;
  if (d >= NN) return;
  const int p0 = indptr[d], p1 = indptr[d+1];

  float aldv[4];
#pragma unroll
  for (int q=0;q<4;q++) aldv[q] = ald[d*4+q];

  float mx[4];
#pragma unroll
  for (int q=0;q<4;q++) mx[q] = -3.4e38f;
  for (int e=p0+lane; e<p1; e+=64){
    int s = csr_src[e];
#pragma unroll
    for (int q=0;q<4;q++){
      float ev = lrelu(als[s*4+q] + aldv[q]);
      mx[q] = fmaxf(mx[q], ev);
    }
  }
#pragma unroll
  for (int off=32; off>=1; off>>=1){
#pragma unroll
    for (int q=0;q<4;q++) mx[q] = fmaxf(mx[q], __shfl_xor(mx[q], off));
  }

  const int q = lane >> 4;
  const float mq = mx[q];
  const float aldq = aldv[q];
  float ax=0.f, ay=0.f, az=0.f, aw=0.f, den=0.f;
  int s_next = (p0 < p1) ? csr_src[p0] : 0;
  for (int e=p0; e<p1; ++e){
    const int s = s_next;
    if (e+1 < p1) s_next = csr_src[e+1];
    float ev = lrelu(als[s*4+q] + aldq);
    float ex = __expf(ev - mq);
    den += ex;
    float4 v = *(const float4*)(xh + (size_t)s*256 + lane*4);
    ax = fmaf(ex, v.x, ax); ay = fmaf(ex, v.y, ay);
    az = fmaf(ex, v.z, az); aw = fmaf(ex, v.w, aw);
  }
  const float rr = 1.0f/(den + 1e-16f);
  const int o = lane*4;
  float v0 = ax*rr + b1g[o+0];
  float v1 = ay*rr + b1g[o+1];
  float v2 = az*rr + b1g[o+2];
  float v3 = aw*rr + b1g[o+3];
  v0 = v0>0.f?v0:0.f; v1 = v1>0.f?v1:0.f; v2 = v2>0.f?v2:0.f; v3 = v3>0.f?v3:0.f;
  float part = v0*w2[o+0] + v1*w2[o+1] + v2*w2[o+2] + v3*w2[o+3];
#pragma unroll
  for (int off=32; off>=1; off>>=1) part += __shfl_xor(part, off);
  if (lane == 0){
    xh2[d] = part;
    a2s[d] = part * as2[0];
    a2d[d] = part * ad2[0];
  }
}

// ---------------- GAT2 gather ----------------
__global__ __launch_bounds__(256) void gat2_gather(
  const int* __restrict__ indptr, const int* __restrict__ csr_src,
  const float* __restrict__ a2s, const float* __restrict__ a2d,
  const float* __restrict__ xh2, const float* __restrict__ b2,
  float* __restrict__ out)
{
  const int d = blockIdx.x*4 + (threadIdx.x >> 6);
  const int lane = threadIdx.x & 63;
  if (d >= NN) return;
  const int p0 = indptr[d], p1 = indptr[d+1];
  const float add = a2d[d];

  float mx = -3.4e38f;
  for (int e=p0+lane; e<p1; e+=64){
    int s = csr_src[e];
    mx = fmaxf(mx, lrelu(a2s[s] + add));
  }
#pragma unroll
  for (int off=32; off>=1; off>>=1) mx = fmaxf(mx, __shfl_xor(mx, off));

  float den = 0.f, num = 0.f;
  for (int e=p0+lane; e<p1; e+=64){
    int s = csr_src[e];
    float ev = lrelu(a2s[s] + add);
    float ex = __expf(ev - mx);
    den += ex;
    num = fmaf(ex, xh2[s], num);
  }
#pragma unroll
  for (int off=32; off>=1; off>>=1){ den += __shfl_xor(den, off); num += __shfl_xor(num, off); }
  if (lane == 0) out[d] = num/(den + 1e-16f) + b2[0];
}

// ---------------- launcher ----------------
extern "C" void kernel_launch(void* const* d_in, const int* in_sizes, int n_in,
                              void* d_out, int out_size, void* d_ws, size_t ws_size,
                              hipStream_t stream)
{
  const float* x    = (const float*)d_in[0];
  const int*   ei   = (const int*)d_in[1];
  const float* Wih0 = (const float*)d_in[2];
  const float* Whh0 = (const float*)d_in[3];
  const float* bih0 = (const float*)d_in[4];
  const float* bhh0 = (const float*)d_in[5];
  const float* Wih1 = (const float*)d_in[6];
  const float* Whh1 = (const float*)d_in[7];
  const float* bih1 = (const float*)d_in[8];
  const float* bhh1 = (const float*)d_in[9];
  const float* g1w  = (const float*)d_in[10];
  const float* g1as = (const float*)d_in[11];
  const float* g1ad = (const float*)d_in[12];
  const float* g1b  = (const float*)d_in[13];
  const float* g2w  = (const float*)d_in[14];
  const float* g2as = (const float*)d_in[15];
  const float* g2ad = (const float*)d_in[16];
  const float* g2b  = (const float*)d_in[17];

  float* ws  = (float*)d_ws;
  unsigned short* Wpk = (unsigned short*)ws;   // 114688 shorts = 57344 f32 slots
  float* b0  = ws + 57344;            // 256
  float* b1  = b0 + 256;              // 256
  float* h1  = b1 + 256;              // 20000*64
  float* xh  = h1 + 1280000;          // 20000*256
  float* als = xh + 5120000;          // 80000
  float* ald = als + 80000;           // 80000
  float* xh2 = ald + 80000;           // 20000
  float* a2s = xh2 + 20000;           // 20000
  float* a2d = a2s + 20000;           // 20000
  int*   deg    = (int*)(a2d + 20000);   // 20000
  int*   indptr = deg + 20000;           // 20001
  int*   cursor = indptr + 20001;        // 20000
  int*   csr    = cursor + 20000;        // 340000

  kzero_int<<<(NN+255)/256, 256, 0, stream>>>(deg, NN);
  pack_weights<<<450, 256, 0, stream>>>(Wih0,Whh0,bih0,bhh0,Wih1,Whh1,bih1,bhh1,Wpk,b0,b1);
  count_deg<<<(ETOT+255)/256, 256, 0, stream>>>(ei, deg);
  scan_deg<<<1, 256, 0, stream>>>(deg, indptr, cursor);
  scatter_edges<<<(ETOT+255)/256, 256, 0, stream>>>(ei, cursor, csr);
  lstm_mfma<<<250, 1024, 0, stream>>>(x, Wpk, b0, b1, h1);
  gat1_prep<<<NN/16, 256, 0, stream>>>(h1, g1w, g1as, g1ad, xh, als, ald);
  gat1_gather<<<(NN+3)/4, 256, 0, stream>>>(indptr, csr, als, ald, xh, g1b, g2w, g2as, g2ad, xh2, a2s, a2d);
  gat2_gather<<<(NN+3)/4, 256, 0, stream>>>(indptr, csr, a2s, a2d, xh2, g2b, (float*)d_out);
}

// Round 13
// 355.199 us; speedup vs baseline: 2.0864x; 1.1409x over previous
//
#include <hip/hip_runtime.h>
#include <math.h>

#define NN   20000
#define TT   32
#define INF_ 32
#define HID  64
#define NH   4
#define EE   320000
#define ETOT (EE + NN)
#define ZRW  328   // shorts/row: 5 chunks x 64 (8 hi + 8 lo per lq-group); 656B = 41 x 16B (odd -> conflict-free b128)
#define NB   80    // nodes per LSTM block; 250*80 = 20000 exact
#define SCB  80    // scan blocks (80 x 250 = 20000)

typedef __attribute__((ext_vector_type(8))) short bf16x8;
typedef __attribute__((ext_vector_type(4))) float f32x4;

static __device__ __forceinline__ float lrelu(float x){ return x>0.0f ? x : 0.2f*x; }

static __device__ __forceinline__ unsigned short f2bf(float f){
  unsigned u = __float_as_uint(f);
  unsigned r = u + 0x7fffu + ((u>>16)&1u);
  return (unsigned short)(r>>16);
}
static __device__ __forceinline__ float bf2f(unsigned short h){ return __uint_as_float(((unsigned)h)<<16); }

// chunk-local permuted position for k' (0..31): frag elem j of lane (ln15,lq) is slot lq*8+j
static __device__ __forceinline__ int zpos(int kq){
  return (kq&3) + (((kq>>4)&1)<<2) + (((kq>>2)&3)<<3);
}

// fused LSTM cell: 5 exp + 2 rcp
static __device__ __forceinline__ float lstm_cell(float gi, float gf, float gg, float go, float& c){
  float ef = __expf(-gf), ei = __expf(-gi), eg = __expf(-2.0f*gg);
  float pN = c*(1.0f+ei)*(1.0f+eg) + (1.0f-eg)*(1.0f+ef);
  float pD = (1.0f+ef)*(1.0f+ei)*(1.0f+eg);
  float cc = pN * __builtin_amdgcn_rcpf(pD);
  c = cc;
  float eo = __expf(-go), ec = __expf(-2.0f*cc);
  return (1.0f-ec) * __builtin_amdgcn_rcpf((1.0f+eo)*(1.0f+ec));
}

static __device__ __forceinline__ void edge_sd(const int* __restrict__ ei, int e, int& s, int& d){
  if (e < EE){ s = ei[e]; d = ei[EE + e]; } else { s = e - EE; d = s; }
}

// ---------------- utility kernels ----------------
__global__ void kzero_int(int* __restrict__ p, int n){
  int i = blockIdx.x*256 + threadIdx.x;
  if (i < n) p[i] = 0;
}

// Pack weights into MFMA A-frag layout, rows permuted so C/D row = 4*unitLocal + gateType. (verified R9-R11)
__global__ void pack_weights(const float* __restrict__ Wih0, const float* __restrict__ Whh0,
                             const float* __restrict__ bih0, const float* __restrict__ bhh0,
                             const float* __restrict__ Wih1, const float* __restrict__ Whh1,
                             const float* __restrict__ bih1, const float* __restrict__ bhh1,
                             unsigned short* __restrict__ Wpk,
                             float* __restrict__ b0, float* __restrict__ b1){
  int idx = blockIdx.x*256 + threadIdx.x;
  if (idx < 49152){
    int fb = idx >> 9;            // (tl*3+ks)*2+h
    int h  = fb & 1;
    int t2 = fb >> 1;
    int ks = t2 % 3, tl = t2 / 3;
    int r  = idx & 511;
    int l  = r >> 3, j = r & 7;
    int pr = l & 15;
    int g  = (pr&3)*64 + tl*4 + (pr>>2);
    int k  = ks*32 + 4*(l>>4) + (j & 3) + 16*(j >> 2);
    float src = (k < 32) ? Wih0[g*32 + k] : Whh0[g*64 + (k - 32)];
    unsigned short hi = f2bf(src);
    Wpk[idx] = h ? f2bf(src - bf2f(hi)) : hi;
  } else if (idx < 114688){
    int idx2 = idx - 49152;
    int fb = idx2 >> 9;           // (tl*4+ks)*2+h
    int h  = fb & 1;
    int t2 = fb >> 1;
    int ks = t2 & 3, tl = t2 >> 2;
    int r  = idx2 & 511;
    int l  = r >> 3, j = r & 7;
    int pr = l & 15;
    int g  = (pr&3)*64 + tl*4 + (pr>>2);
    int k  = ks*32 + 4*(l>>4) + (j & 3) + 16*(j >> 2);
    float src = (k < 64) ? Wih1[g*64 + k] : Whh1[g*64 + (k - 64)];
    unsigned short hi = f2bf(src);
    Wpk[idx] = h ? f2bf(src - bf2f(hi)) : hi;
  } else {
    int m = idx - 114688;
    if (m < 256) b0[m] = bih0[m] + bhh0[m];
    else if (m < 512) b1[m-256] = bih1[m-256] + bhh1[m-256];
  }
}

// ---------------- CSR build (dst-indexed), parallel scan ----------------
__global__ void count_deg(const int* __restrict__ ei, int* __restrict__ deg){
  int e = blockIdx.x*256 + threadIdx.x;
  if (e >= ETOT) return;
  int s, d; edge_sd(ei, e, s, d);
  atomicAdd(deg + d, 1);
}

__global__ void scan_part(const int* __restrict__ deg, int* __restrict__ part){
  __shared__ int s[256];
  const int b = blockIdx.x, t = threadIdx.x;
  int v = (t < 250) ? deg[b*250 + t] : 0;
  s[t] = v; __syncthreads();
  for (int off=128; off>=1; off>>=1){ if (t<off) s[t]+=s[t+off]; __syncthreads(); }
  if (t==0) part[b] = s[0];
}

__global__ void scan_tops(int* __restrict__ part){
  if (threadIdx.x==0){
    int run=0;
    for (int i=0;i<SCB;i++){ int v=part[i]; part[i]=run; run+=v; }
  }
}

__global__ void scan_fill(const int* __restrict__ deg, const int* __restrict__ part,
                          int* __restrict__ indptr, int* __restrict__ cursor){
  __shared__ int s[256];
  const int b = blockIdx.x, t = threadIdx.x;
  int v = (t < 250) ? deg[b*250 + t] : 0;
  s[t] = v; __syncthreads();
  int val = v;
  for (int off=1; off<256; off<<=1){
    int add = (t>=off) ? s[t-off] : 0;
    __syncthreads();
    val += add; s[t] = val;
    __syncthreads();
  }
  int excl = val - v + part[b];
  if (t < 250){ indptr[b*250 + t] = excl; cursor[b*250 + t] = excl; }
  if (b == SCB-1 && t == 0) indptr[NN] = ETOT;
}

__global__ void scatter_edges(const int* __restrict__ ei, int* __restrict__ cursor, int* __restrict__ csr_src){
  int e = blockIdx.x*256 + threadIdx.x;
  if (e >= ETOT) return;
  int s, d; edge_sd(ei, e, s, d);
  int pos = atomicAdd(cursor + d, 1);
  csr_src[pos] = s;
}

// pin a 16B weight fragment into VGPRs: opaque to compiler -> cannot be rematerialized
#define PIN_LOAD(dst, p) asm volatile( \
    "global_load_dwordx4 %0, %1, off\n\t" \
    "s_waitcnt vmcnt(0)" \
    : "=&v"(dst) : "v"(p))

// ---------------- MFMA split-bf16 2-layer LSTM: interleaved hi/lo Z, conflict-free b128 ----------------
// Z row (node) = 5 chunks x 64 shorts; chunk = 4 lq-groups x [8 hi | 8 lo].
// Row stride 656B = 41 x 16B (odd) -> wave's b128 frag reads spread over all 8 phases, conflict-free.
__global__ __launch_bounds__(1024)
__attribute__((amdgpu_waves_per_eu(4, 4)))
void lstm_mfma(
    const float* __restrict__ x,
    const unsigned short* __restrict__ Wpk,
    const float* __restrict__ b0, const float* __restrict__ b1,
    float* __restrict__ h1out)
{
  __shared__ unsigned short Zc[NB*ZRW];   // 52.5 KB

  const int tid  = threadIdx.x;
  const int lane = tid & 63;
  const int w    = __builtin_amdgcn_readfirstlane(tid >> 6);   // 0..15
  const int ln15 = lane & 15;
  const int lq   = lane >> 4;                                  // 0..3
  const int gbase = blockIdx.x * NB;

  const bf16x8* wp = (const bf16x8*)Wpk;

  // ---- pin 14 weight fragments in registers (56 VGPRs) ----
  bf16x8 wA0h[3], wA0l[3], wA1h[4], wA1l[4];
#pragma unroll
  for (int ks=0; ks<3; ++ks){
    PIN_LOAD(wA0h[ks], wp + ((w*3+ks)*2+0)*64 + lane);
    PIN_LOAD(wA0l[ks], wp + ((w*3+ks)*2+1)*64 + lane);
  }
#pragma unroll
  for (int ks=0; ks<4; ++ks){
    PIN_LOAD(wA1h[ks], wp + 6144 + ((w*4+ks)*2+0)*64 + lane);
    PIN_LOAD(wA1l[ks], wp + 6144 + ((w*4+ks)*2+1)*64 + lane);
  }

  // bias per lane: bv[j] = b[j*64 + w*4 + lq]
  f32x4 bv0, bv1;
  {
    const int u = w*4 + lq;
#pragma unroll
    for (int j=0; j<4; ++j){ bv0[j] = b0[j*64+u]; bv1[j] = b1[j*64+u]; }
  }

  // pointwise H-write hi-columns for unit u = w*4+lq (lo at +8):
  // slot p = zpos(u&31): p&7 = lq + 4*((w>>2)&1), p>>3 = w&3
  const int colbase = ((w&3)<<4) + lq + (((w>>2)&1)<<2);
  const int uc0 = (1 + (w>>3))*64 + colbase;   // h0 chunk
  const int uc1 = (3 + (w>>3))*64 + colbase;   // h1 chunk

  // x staging: threads 0..639, one quad each: node xn=tid>>3, k=(tid&7)*4 -> chunk 0 slots
  const int xn = tid >> 3;
  const int xk = (tid & 7) * 4;
  const int p0 = (((xk>>4)&1)<<2) + (((xk>>2)&3)<<3);   // zpos of k=xk (quad-aligned)
  const int xoff = ((p0>>3)<<4) + (p0&7);               // hi short offset in chunk 0
  const float* xp = x + (size_t)(gbase + ((xn < NB) ? xn : 0))*(TT*INF_) + xk;
  const bool xth = (tid < 640);

// packed bf16 hi/lo staging of a float4 into Zc chunk 0
#define XSTAGE(v) {                                                       \
    unsigned pkA, pkB, plA, plB;                                          \
    asm("v_cvt_pk_bf16_f32 %0,%1,%2":"=v"(pkA):"v"((v).x),"v"((v).y));    \
    asm("v_cvt_pk_bf16_f32 %0,%1,%2":"=v"(pkB):"v"((v).z),"v"((v).w));    \
    float l0_ = (v).x - __uint_as_float(pkA<<16);                         \
    float l1_ = (v).y - __uint_as_float(pkA & 0xffff0000u);               \
    float l2_ = (v).z - __uint_as_float(pkB<<16);                         \
    float l3_ = (v).w - __uint_as_float(pkB & 0xffff0000u);               \
    asm("v_cvt_pk_bf16_f32 %0,%1,%2":"=v"(plA):"v"(l0_),"v"(l1_));        \
    asm("v_cvt_pk_bf16_f32 %0,%1,%2":"=v"(plB):"v"(l2_),"v"(l3_));        \
    *(uint2*)&Zc[xn*ZRW + xoff]     = make_uint2(pkA, pkB);               \
    *(uint2*)&Zc[xn*ZRW + xoff + 8] = make_uint2(plA, plB); }

  // ---- prologue: zero Z, stage x(0) ----
  for (int i = tid; i < NB*ZRW/2; i += 1024) ((unsigned*)Zc)[i] = 0;
  __syncthreads();
  if (xth){
    float4 v = *(const float4*)xp;
    XSTAGE(v);
  }
  __syncthreads();

  float c0[5], c1[5];
#pragma unroll
  for (int i=0;i<5;i++){ c0[i]=0.f; c1[i]=0.f; }
  f32x4 aL1[5];

#define MF(acc, A, B) acc = __builtin_amdgcn_mfma_f32_16x16x32_bf16((A),(B),(acc),0,0,0)

// write a PAIR of h values (rows GA*16+ln15, GB*16+ln15) at hi-col colh (lo at +8)
#define WPAIR(ha, hb, GA, GB, colh) {                                     \
    unsigned pk_, pl_;                                                    \
    asm("v_cvt_pk_bf16_f32 %0,%1,%2":"=v"(pk_):"v"(ha),"v"(hb));          \
    float la_ = (ha) - __uint_as_float(pk_<<16);                          \
    float lb_ = (hb) - __uint_as_float(pk_ & 0xffff0000u);                \
    asm("v_cvt_pk_bf16_f32 %0,%1,%2":"=v"(pl_):"v"(la_),"v"(lb_));        \
    Zc[((GA)*16+ln15)*ZRW + (colh)]     = (unsigned short)pk_;            \
    Zc[((GB)*16+ln15)*ZRW + (colh)]     = (unsigned short)(pk_>>16);      \
    Zc[((GA)*16+ln15)*ZRW + (colh) + 8] = (unsigned short)pl_;            \
    Zc[((GB)*16+ln15)*ZRW + (colh) + 8] = (unsigned short)(pl_>>16); }

#define WSINGLE(hv, GG, colh) {                                           \
    const int _n = (GG)*16 + ln15;                                        \
    const unsigned short _hh = f2bf(hv);                                  \
    Zc[_n*ZRW + (colh)]     = _hh;                                        \
    Zc[_n*ZRW + (colh) + 8] = f2bf((hv) - bf2f(_hh)); }

#define CHUNK(ACCS, CK, WH, WL)                                           \
    _Pragma("unroll")                                                     \
    for (int GG=0; GG<5; ++GG){                                           \
      const int nd_ = GG*16 + ln15;                                       \
      const bf16x8 zh = *(const bf16x8*)&Zc[nd_*ZRW + (CK)*64 + lq*16];   \
      const bf16x8 zl = *(const bf16x8*)&Zc[nd_*ZRW + (CK)*64 + lq*16+8]; \
      MF(ACCS[GG], WH, zh); MF(ACCS[GG], WH, zl); MF(ACCS[GG], WL, zh);   \
    }

  for (int t=0; t<TT; ++t){
    // ====== P1: x(t+1) load issue; L0 chunk0; L1-cells(t-1)->H1; L0 chunks 1,2 ======
    float4 xv;
    const bool dox = xth && (t+1 < TT);
    if (dox) xv = *(const float4*)(xp + (size_t)(t+1)*INF_);

    f32x4 aL0[5];
#pragma unroll
    for (int GG=0; GG<5; ++GG) aL0[GG] = bv0;

    CHUNK(aL0, 0, wA0h[0], wA0l[0]);          // x slab

    if (t > 0){
      float h0_ = lstm_cell(aL1[0][0], aL1[0][1], aL1[0][2], aL1[0][3], c1[0]);
      float h1_ = lstm_cell(aL1[1][0], aL1[1][1], aL1[1][2], aL1[1][3], c1[1]);
      float h2_ = lstm_cell(aL1[2][0], aL1[2][1], aL1[2][2], aL1[2][3], c1[2]);
      float h3_ = lstm_cell(aL1[3][0], aL1[3][1], aL1[3][2], aL1[3][3], c1[3]);
      float h4_ = lstm_cell(aL1[4][0], aL1[4][1], aL1[4][2], aL1[4][3], c1[4]);
      WPAIR(h0_, h1_, 0, 1, uc1); WPAIR(h2_, h3_, 2, 3, uc1); WSINGLE(h4_, 4, uc1);
    }

    CHUNK(aL0, 1, wA0h[1], wA0l[1]);          // h0 slab a
    CHUNK(aL0, 2, wA0h[2], wA0l[2]);          // h0 slab b
    __syncthreads();

    // ====== P2: L1 chunks 3,4 (H1(t-1)); L0-cells->H0 + x(t+1) write ======
#pragma unroll
    for (int GG=0; GG<5; ++GG) aL1[GG] = bv1;

    CHUNK(aL1, 3, wA1h[2], wA1l[2]);          // h1 slab a

    {
      float h0_ = lstm_cell(aL0[0][0], aL0[0][1], aL0[0][2], aL0[0][3], c0[0]);
      float h1_ = lstm_cell(aL0[1][0], aL0[1][1], aL0[1][2], aL0[1][3], c0[1]);
      float h2_ = lstm_cell(aL0[2][0], aL0[2][1], aL0[2][2], aL0[2][3], c0[2]);
      float h3_ = lstm_cell(aL0[3][0], aL0[3][1], aL0[3][2], aL0[3][3], c0[3]);
      float h4_ = lstm_cell(aL0[4][0], aL0[4][1], aL0[4][2], aL0[4][3], c0[4]);
      WPAIR(h0_, h1_, 0, 1, uc0); WPAIR(h2_, h3_, 2, 3, uc0); WSINGLE(h4_, 4, uc0);
    }
    if (dox) XSTAGE(xv);

    CHUNK(aL1, 4, wA1h[3], wA1l[3]);          // h1 slab b
    __syncthreads();

    // ====== P3: L1 chunks 1,2 (H0 just written) — no trailing barrier ======
    CHUNK(aL1, 1, wA1h[0], wA1l[0]);
    CHUNK(aL1, 2, wA1h[1], wA1l[1]);
    // safe: next P1 writes H1 (chunks 3,4) / reads x(0),H0(1,2) — disjoint from P3 reads
  }

  // final L1 cells -> H1
  {
    float h0_ = lstm_cell(aL1[0][0], aL1[0][1], aL1[0][2], aL1[0][3], c1[0]);
    float h1_ = lstm_cell(aL1[1][0], aL1[1][1], aL1[1][2], aL1[1][3], c1[1]);
    float h2_ = lstm_cell(aL1[2][0], aL1[2][1], aL1[2][2], aL1[2][3], c1[2]);
    float h3_ = lstm_cell(aL1[3][0], aL1[3][1], aL1[3][2], aL1[3][3], c1[3]);
    float h4_ = lstm_cell(aL1[4][0], aL1[4][1], aL1[4][2], aL1[4][3], c1[4]);
    WPAIR(h0_, h1_, 0, 1, uc1); WPAIR(h2_, h3_, 2, 3, uc1); WSINGLE(h4_, 4, uc1);
  }
  __syncthreads();

  // epilogue: coalesced h1 write (h1 unit u -> chunk 3+(u>>5), slot zpos(u&31))
  for (int o = tid; o < NB*64; o += 1024){
    const int n = o >> 6, u = o & 63;
    const int p = zpos(u & 31);
    const int ch = (3 + (u>>5))*64 + ((p>>3)<<4) + (p&7);
    h1out[(size_t)(gbase+n)*64 + u] = bf2f(Zc[n*ZRW + ch]) + bf2f(Zc[n*ZRW + ch + 8]);
  }
#undef MF
#undef WPAIR
#undef WSINGLE
#undef CHUNK
#undef XSTAGE
}

// ---------------- GAT layer 1 prep: 32 nodes/block (amortize W reads) ----------------
__global__ __launch_bounds__(256) void gat1_prep(const float* __restrict__ h1, const float* __restrict__ W,
  const float* __restrict__ as_, const float* __restrict__ ad_,
  float* __restrict__ xh, float* __restrict__ als, float* __restrict__ ald)
{
  __shared__ float hs[32][64];
  const int nb0 = blockIdx.x * 32;
  const int o  = threadIdx.x;
  const int q  = o >> 6, u = o & 63;
  for (int i = o; i < 2048; i += 256){
    hs[i>>6][i&63] = h1[(size_t)(nb0 + (i>>6))*64 + (i&63)];
  }
  __syncthreads();
  float acc[32];
#pragma unroll
  for (int nd=0; nd<32; ++nd) acc[nd] = 0.f;
  for (int k=0; k<64; ++k){
    const float wv = W[k*256 + o];
#pragma unroll
    for (int nd=0; nd<32; ++nd) acc[nd] = fmaf(hs[nd][k], wv, acc[nd]);
  }
  const float asv = as_[o], adv = ad_[o];
#pragma unroll
  for (int nd=0; nd<32; ++nd){
    xh[(size_t)(nb0+nd)*256 + o] = acc[nd];
    float ps = acc[nd] * asv;
    float pd = acc[nd] * adv;
#pragma unroll
    for (int off=32; off>=1; off>>=1){ ps += __shfl_xor(ps, off); pd += __shfl_xor(pd, off); }
    if (u == 0){ als[(nb0+nd)*4 + q] = ps; ald[(nb0+nd)*4 + q] = pd; }
  }
}

// ---------------- GAT1 gather + fused epilogue ----------------
__global__ __launch_bounds__(256) void gat1_gather(
  const int* __restrict__ indptr, const int* __restrict__ csr_src,
  const float* __restrict__ als, const float* __restrict__ ald,
  const float* __restrict__ xh,  const float* __restrict__ b1g,
  const float* __restrict__ w2,  const float* __restrict__ as2, const float* __restrict__ ad2,
  float* __restrict__ xh2, float* __restrict__ a2s, float* __restrict__ a2d)
{
  const int d = blockIdx.x*4 + (threadIdx.x >> 6);
  const int lane = threadIdx.x & 63;
  if (d >= NN) return;
  const int p0 = indptr[d], p1 = indptr[d+1];

  float aldv[4];
#pragma unroll
  for (int q=0;q<4;q++) aldv[q] = ald[d*4+q];

  float mx[4];
#pragma unroll
  for (int q=0;q<4;q++) mx[q] = -3.4e38f;
  for (int e=p0+lane; e<p1; e+=64){
    int s = csr_src[e];
#pragma unroll
    for (int q=0;q<4;q++){
      float ev = lrelu(als[s*4+q] + aldv[q]);
      mx[q] = fmaxf(mx[q], ev);
    }
  }
#pragma unroll
  for (int off=32; off>=1; off>>=1){
#pragma unroll
    for (int q=0;q<4;q++) mx[q] = fmaxf(mx[q], __shfl_xor(mx[q], off));
  }

  const int q = lane >> 4;
  const float mq = mx[q];
  const float aldq = aldv[q];
  float ax=0.f, ay=0.f, az=0.f, aw=0.f, den=0.f;
  int s_next = (p0 < p1) ? csr_src[p0] : 0;
  for (int e=p0; e<p1; ++e){
    const int s = s_next;
    if (e+1 < p1) s_next = csr_src[e+1];
    float ev = lrelu(als[s*4+q] + aldq);
    float ex = __expf(ev - mq);
    den += ex;
    float4 v = *(const float4*)(xh + (size_t)s*256 + lane*4);
    ax = fmaf(ex, v.x, ax); ay = fmaf(ex, v.y, ay);
    az = fmaf(ex, v.z, az); aw = fmaf(ex, v.w, aw);
  }
  const float rr = 1.0f/(den + 1e-16f);
  const int o = lane*4;
  float v0 = ax*rr + b1g[o+0];
  float v1 = ay*rr + b1g[o+1];
  float v2 = az*rr + b1g[o+2];
  float v3 = aw*rr + b1g[o+3];
  v0 = v0>0.f?v0:0.f; v1 = v1>0.f?v1:0.f; v2 = v2>0.f?v2:0.f; v3 = v3>0.f?v3:0.f;
  float part = v0*w2[o+0] + v1*w2[o+1] + v2*w2[o+2] + v3*w2[o+3];
#pragma unroll
  for (int off=32; off>=1; off>>=1) part += __shfl_xor(part, off);
  if (lane == 0){
    xh2[d] = part;
    a2s[d] = part * as2[0];
    a2d[d] = part * ad2[0];
  }
}

// ---------------- GAT2 gather ----------------
__global__ __launch_bounds__(256) void gat2_gather(
  const int* __restrict__ indptr, const int* __restrict__ csr_src,
  const float* __restrict__ a2s, const float* __restrict__ a2d,
  const float* __restrict__ xh2, const float* __restrict__ b2,
  float* __restrict__ out)
{
  const int d = blockIdx.x*4 + (threadIdx.x >> 6);
  const int lane = threadIdx.x & 63;
  if (d >= NN) return;
  const int p0 = indptr[d], p1 = indptr[d+1];
  const float add = a2d[d];

  float mx = -3.4e38f;
  for (int e=p0+lane; e<p1; e+=64){
    int s = csr_src[e];
    mx = fmaxf(mx, lrelu(a2s[s] + add));
  }
#pragma unroll
  for (int off=32; off>=1; off>>=1) mx = fmaxf(mx, __shfl_xor(mx, off));

  float den = 0.f, num = 0.f;
  for (int e=p0+lane; e<p1; e+=64){
    int s = csr_src[e];
    float ev = lrelu(a2s[s] + add);
    float ex = __expf(ev - mx);
    den += ex;
    num = fmaf(ex, xh2[s], num);
  }
#pragma unroll
  for (int off=32; off>=1; off>>=1){ den += __shfl_xor(den, off); num += __shfl_xor(num, off); }
  if (lane == 0) out[d] = num/(den + 1e-16f) + b2[0];
}

// ---------------- launcher ----------------
extern "C" void kernel_launch(void* const* d_in, const int* in_sizes, int n_in,
                              void* d_out, int out_size, void* d_ws, size_t ws_size,
                              hipStream_t stream)
{
  const float* x    = (const float*)d_in[0];
  const int*   ei   = (const int*)d_in[1];
  const float* Wih0 = (const float*)d_in[2];
  const float* Whh0 = (const float*)d_in[3];
  const float* bih0 = (const float*)d_in[4];
  const float* bhh0 = (const float*)d_in[5];
  const float* Wih1 = (const float*)d_in[6];
  const float* Whh1 = (const float*)d_in[7];
  const float* bih1 = (const float*)d_in[8];
  const float* bhh1 = (const float*)d_in[9];
  const float* g1w  = (const float*)d_in[10];
  const float* g1as = (const float*)d_in[11];
  const float* g1ad = (const float*)d_in[12];
  const float* g1b  = (const float*)d_in[13];
  const float* g2w  = (const float*)d_in[14];
  const float* g2as = (const float*)d_in[15];
  const float* g2ad = (const float*)d_in[16];
  const float* g2b  = (const float*)d_in[17];

  float* ws  = (float*)d_ws;
  unsigned short* Wpk = (unsigned short*)ws;   // 114688 shorts = 57344 f32 slots
  float* b0  = ws + 57344;            // 256
  float* b1  = b0 + 256;              // 256
  float* h1  = b1 + 256;              // 20000*64
  float* xh  = h1 + 1280000;          // 20000*256
  float* als = xh + 5120000;          // 80000
  float* ald = als + 80000;           // 80000
  float* xh2 = ald + 80000;           // 20000
  float* a2s = xh2 + 20000;           // 20000
  float* a2d = a2s + 20000;           // 20000
  int*   deg    = (int*)(a2d + 20000);   // 20000
  int*   indptr = deg + 20000;           // 20001
  int*   cursor = indptr + 20001;        // 20000
  int*   csr    = cursor + 20000;        // 340000
  int*   spart  = csr + 340000;          // 80

  kzero_int<<<(NN+255)/256, 256, 0, stream>>>(deg, NN);
  pack_weights<<<450, 256, 0, stream>>>(Wih0,Whh0,bih0,bhh0,Wih1,Whh1,bih1,bhh1,Wpk,b0,b1);
  count_deg<<<(ETOT+255)/256, 256, 0, stream>>>(ei, deg);
  scan_part<<<SCB, 256, 0, stream>>>(deg, spart);
  scan_tops<<<1, 64, 0, stream>>>(spart);
  scan_fill<<<SCB, 256, 0, stream>>>(deg, spart, indptr, cursor);
  scatter_edges<<<(ETOT+255)/256, 256, 0, stream>>>(ei, cursor, csr);
  lstm_mfma<<<250, 1024, 0, stream>>>(x, Wpk, b0, b1, h1);
  gat1_prep<<<NN/32, 256, 0, stream>>>(h1, g1w, g1as, g1ad, xh, als, ald);
  gat1_gather<<<(NN+3)/4, 256, 0, stream>>>(indptr, csr, als, ald, xh, g1b, g2w, g2as, g2ad, xh2, a2s, a2d);
  gat2_gather<<<(NN+3)/4, 256, 0, stream>>>(indptr, csr, a2s, a2d, xh2, g2b, (float*)d_out);
}